// Round 15
// baseline (376.391 us; speedup 1.0000x reference)
//
#include <hip/hip_runtime.h>
#include <hip/hip_bf16.h>

// ---------------------------------------------------------------------------
// Multihead attention (single 512-wide head), b=4, n=4096, d=inner=512, fp32 io.
//   qk = x@[Wq*s | Wk]^T   (merged projection, 8-phase 256^2 kernel)
//   vw = y@(Wo@Wv)^T       (out-proj folded into V), stored transposed as vwT
//   P  = exp(q@k^T)        (no max subtraction: |S| small, fp32-safe)
//   out = (P@vw)/rowsum(P) + bo   (split-K=2 PV + deterministic reduce)
// R15: S-GEMM is PERSISTENT (256 blocks x 4 tiles, continuous pipeline —
//      inter-tile prologue staged by phases i3/m1..m3, epilogue overlapped);
//      prep (cvt x/y + cvt W + wvo) merged into one launch.
// ---------------------------------------------------------------------------

typedef unsigned short u16;
typedef __bf16 bf16x8 __attribute__((ext_vector_type(8)));
typedef float f32x4 __attribute__((ext_vector_type(4)));

#define SCALE_QK 0.044194173824159216f /* 1/sqrt(512) */

__device__ __forceinline__ u16 f2bf(float f) {
    __hip_bfloat16 h = __float2bfloat16(f);
    return __builtin_bit_cast(u16, h);
}

__device__ __forceinline__ void load_lds16(const void* g, void* l) {
    __builtin_amdgcn_global_load_lds(
        (const __attribute__((address_space(1))) void*)g,
        (__attribute__((address_space(3))) void*)l, 16, 0, 0);
}

// ---------------- prep: x/y -> bf16, [Wq*s|Wk] -> bf16, Wvo=Wo@Wv -> bf16 ---
__global__ void prep_kernel(const float* __restrict__ x, const float* __restrict__ y,
                            const float* __restrict__ Wq, const float* __restrict__ Wk,
                            const float* __restrict__ Wo, const float* __restrict__ Wv,
                            u16* __restrict__ xb, u16* __restrict__ Wqkb,
                            u16* __restrict__ Wvob) {
    const int b = blockIdx.x, tid = threadIdx.x;
    if (b < 8448) {
        const float *s0, *s1;
        u16* dst;
        int n8, i;
        float sc0, sc1;
        if (b < 8192) { s0 = x;  s1 = y;  dst = xb;   n8 = 1048576; sc0 = 1.f;      sc1 = 1.f; i = b * 256 + tid; }
        else          { s0 = Wq; s1 = Wk; dst = Wqkb; n8 = 32768;   sc0 = SCALE_QK; sc1 = 1.f; i = (b - 8192) * 256 + tid; }
        const float4* s4;
        float scale;
        int j;
        if (i < n8) { s4 = (const float4*)s0; scale = sc0; j = i; }
        else        { s4 = (const float4*)s1; scale = sc1; j = i - n8; }
        float4 v0 = s4[2 * j], v1 = s4[2 * j + 1];
        union { u16 u[8]; uint4 v; } o;
        o.u[0] = f2bf(v0.x * scale); o.u[1] = f2bf(v0.y * scale);
        o.u[2] = f2bf(v0.z * scale); o.u[3] = f2bf(v0.w * scale);
        o.u[4] = f2bf(v1.x * scale); o.u[5] = f2bf(v1.y * scale);
        o.u[6] = f2bf(v1.z * scale); o.u[7] = f2bf(v1.w * scale);
        ((uint4*)dst)[i] = o.v;
    } else {
        // Wvo = Wo @ Wv -> bf16, 4 rows per block (blocks 8448..8575)
        int ob = (b - 8448) * 4, t = tid;
        float a[4][2] = {{0.f, 0.f}, {0.f, 0.f}, {0.f, 0.f}, {0.f, 0.f}};
        for (int i = 0; i < 512; ++i) {
            float v0 = Wv[i * 512 + t], v1 = Wv[i * 512 + t + 256];
#pragma unroll
            for (int r = 0; r < 4; ++r) {
                float w = Wo[(ob + r) * 512 + i];
                a[r][0] += w * v0;
                a[r][1] += w * v1;
            }
        }
#pragma unroll
        for (int r = 0; r < 4; ++r) {
            Wvob[(ob + r) * 512 + t] = f2bf(a[r][0]);
            Wvob[(ob + r) * 512 + t + 256] = f2bf(a[r][1]);
        }
    }
}

// ===========================================================================
// 256x256 merged-phase GEMM, K=512, PERSISTENT over TPB output tiles (z = t).
// C = (DOEXP ? exp : id)(A@B^T) -> bf16. 8 waves (2M x 4N), wave 128x64;
// 8 slots x 16KB; 32 MFMA per barrier pair; continuous vmcnt(4) pipeline:
// phases (i3, m1..m3) stage the NEXT tile's prologue halves 0..5 (slots 0..5,
// 3-phase lookahead = steady state); epilogue overlaps the staging window.
// ===========================================================================
template <int DOEXP, int TPB>
__launch_bounds__(512, 2)
__global__ void gemm256_kernel(const u16* __restrict__ A, const u16* __restrict__ B,
                               u16* __restrict__ Cout, int N, int lda, int ldb,
                               long long sAz, long long sBz, long long sCz) {
    __shared__ u16 lds[8][8192];

    const int tid = threadIdx.x;
    const int wave = tid >> 6, lane = tid & 63;
    const int lr = lane & 15, lg = lane >> 4;
    const int wm = wave >> 2, wn = wave & 3;
    const int rsw = (lg ^ ((lr >> 1) & 3)) << 3;  // read-side swizzled k-group*8

    const int gx = gridDim.x, gy = gridDim.y;
    int bid = blockIdx.y * gx + blockIdx.x;
    const int nwg = gx * gy;
    int lgc = (bid & 7) * (nwg >> 3) + (bid >> 3);
    const int bx = lgc % gx, by = lgc / gx;
    const int row0 = by * 256, col0 = bx * 256;

    const int rb = lane >> 2;
    const int kg8 = ((lane & 3) ^ ((rb >> 1) & 3)) << 3;  // stage-side swizzle

#define STAGE_HALF(Ab_, Bb_, s_, slot_)                                           \
    {                                                                             \
        const int h_ = (s_)&3, ts_ = (s_) >> 2;                                   \
        const u16* G_ = (h_ & 1) ? (Bb_) : (Ab_);                                 \
        const int pan_ = (h_ & 1) ? col0 : row0;                                  \
        const int ld_ = (h_ & 1) ? ldb : lda;                                     \
        const int kofs_ = ts_ * 64 + (h_ >> 1) * 32 + kg8;                        \
        _Pragma("unroll") for (int j_ = 0; j_ < 2; ++j_) {                        \
            int r_ = (j_ * 8 + wave) * 16 + rb;                                   \
            load_lds16(G_ + (size_t)(pan_ + r_) * ld_ + kofs_,                    \
                       &lds[slot_][(j_ * 8 + wave) * 512]);                       \
        }                                                                         \
    }

    // prologue: tile 0, halves 0..5 -> slots 0..5
    #pragma unroll
    for (int s = 0; s < 6; ++s) STAGE_HALF(A, B, s, s);
    asm volatile("s_waitcnt vmcnt(4)");
    __builtin_amdgcn_s_barrier();

    for (int t = 0; t < TPB; ++t) {
        const u16* Ab = A + (size_t)t * sAz;
        const u16* Bb = B + (size_t)t * sBz;
        const u16* Abn = A + (size_t)(t + 1) * sAz;  // used only if t+1 < TPB
        const u16* Bbn = B + (size_t)(t + 1) * sBz;

        f32x4 acc[8][4];
#pragma unroll
        for (int i = 0; i < 8; ++i)
#pragma unroll
            for (int j = 0; j < 4; ++j) acc[i][j] = (f32x4){0.f, 0.f, 0.f, 0.f};

#pragma unroll
        for (int i = 0; i < 4; ++i) {
#pragma unroll
            for (int m = 0; m < 4; ++m) {       // merged phase
                const int sub = m & 1;          // k-half within K-tile
                const int tp = (m >> 1) & 1;    // K-tile parity
                const int aslot = tp * 4 + 2 * sub;
                const int bslot = aslot + 1;

                bf16x8 af[8];
#pragma unroll
                for (int f = 0; f < 8; ++f) {
                    int row = wm * 128 + f * 16 + lr;
                    af[f] = *(const bf16x8*)&lds[aslot][row * 32 + rsw];
                }
                bf16x8 bfr[4];
#pragma unroll
                for (int f = 0; f < 4; ++f) {
                    int row = wn * 64 + f * 16 + lr;
                    bfr[f] = *(const bf16x8*)&lds[bslot][row * 32 + rsw];
                }

                {
                    const int s0 = 8 * i + 2 * m + 6;
                    if (s0 < 32) {
                        STAGE_HALF(Ab, Bb, s0, (2 * m + 6) & 7);
                        STAGE_HALF(Ab, Bb, s0 + 1, (2 * m + 7) & 7);
                    } else if (t + 1 < TPB) {
                        // stage next tile's prologue halves (0..5) seamlessly
                        STAGE_HALF(Abn, Bbn, s0 - 32, (2 * m + 6) & 7);
                        STAGE_HALF(Abn, Bbn, s0 - 31, (2 * m + 7) & 7);
                    }
                }

                __builtin_amdgcn_s_barrier();

                __builtin_amdgcn_s_setprio(1);
#pragma unroll
                for (int f = 0; f < 8; ++f)
#pragma unroll
                    for (int n = 0; n < 4; ++n)
                        acc[f][n] = __builtin_amdgcn_mfma_f32_16x16x32_bf16(
                            af[f], bfr[n], acc[f][n], 0, 0, 0);
                __builtin_amdgcn_s_setprio(0);

                if (sub == 1) {
                    if (t == TPB - 1 && i == 3 && m == 1)
                        asm volatile("s_waitcnt vmcnt(0)");
                    else
                        asm volatile("s_waitcnt vmcnt(4)");
                }
                __builtin_amdgcn_s_barrier();
            }
        }

        // epilogue for tile t (acc-only; stores overlap next tile's staging)
        u16* C = Cout + (size_t)t * sCz;
#pragma unroll
        for (int fm = 0; fm < 8; ++fm)
#pragma unroll
            for (int fn = 0; fn < 4; ++fn)
#pragma unroll
                for (int reg = 0; reg < 4; ++reg) {
                    int r = row0 + wm * 128 + fm * 16 + lg * 4 + reg;
                    int c = col0 + wn * 64 + fn * 16 + lr;
                    float v = acc[fm][fn][reg];
                    if (DOEXP) v = __expf(v);
                    C[(size_t)r * N + c] = f2bf(v);
                }
    }
#undef STAGE_HALF
}

// ===========================================================================
// 256x256 PV: part[ks] = P[:, ks-half] @ vw[ks-half], inline rowsum.
// 256 blocks (1/CU), 32 K-tiles = 64 merged phases. lda = ldb = 4096.
// ===========================================================================
__launch_bounds__(512, 2)
__global__ void pv8_kernel(const u16* __restrict__ P, const u16* __restrict__ vwT,
                           float* __restrict__ part, float* __restrict__ lpart) {
    __shared__ u16 lds[8][8192];

    const int tid = threadIdx.x;
    const int wave = tid >> 6, lane = tid & 63;
    const int lr = lane & 15, lg = lane >> 4;
    const int wm = wave >> 2, wn = wave & 3;
    const int rsw = (lg ^ ((lr >> 1) & 3)) << 3;

    int bid = blockIdx.x;
    int lgc = (bid & 7) * 32 + (bid >> 3);
    const int rp = lgc & 15;
    const int t5 = lgc >> 4;
    const int cx = t5 & 1, ks = (t5 >> 1) & 1, z = t5 >> 2;
    const int row0 = rp * 256;
    const int col0 = cx * 256;

    const u16* Ab = P + (size_t)z * 16777216 + (size_t)ks * 2048;
    const u16* Bb = vwT + (size_t)z * 2097152 + (size_t)ks * 2048;

    const int rb = lane >> 2;
    const int kg8 = ((lane & 3) ^ ((rb >> 1) & 3)) << 3;

    f32x4 acc[8][4];
#pragma unroll
    for (int i = 0; i < 8; ++i)
#pragma unroll
        for (int j = 0; j < 4; ++j) acc[i][j] = (f32x4){0.f, 0.f, 0.f, 0.f};
    float rsm[8] = {0.f, 0.f, 0.f, 0.f, 0.f, 0.f, 0.f, 0.f};

#define STAGE_HALF(s_, slot_)                                                     \
    {                                                                             \
        const int h_ = (s_)&3, ts_ = (s_) >> 2;                                   \
        const u16* G_ = (h_ & 1) ? Bb : Ab;                                       \
        const int pan_ = (h_ & 1) ? col0 : row0;                                  \
        const int kofs_ = ts_ * 64 + (h_ >> 1) * 32 + kg8;                        \
        _Pragma("unroll") for (int j_ = 0; j_ < 2; ++j_) {                        \
            int r_ = (j_ * 8 + wave) * 16 + rb;                                   \
            load_lds16(G_ + (size_t)(pan_ + r_) * 4096 + kofs_,                   \
                       &lds[slot_][(j_ * 8 + wave) * 512]);                       \
        }                                                                         \
    }

    #pragma unroll
    for (int s = 0; s < 6; ++s) STAGE_HALF(s, s);
    asm volatile("s_waitcnt vmcnt(4)");
    __builtin_amdgcn_s_barrier();

    for (int i = 0; i < 16; ++i) {
#pragma unroll
        for (int m = 0; m < 4; ++m) {           // merged phase
            const int sub = m & 1;
            const int tp = (m >> 1) & 1;
            const int aslot = tp * 4 + 2 * sub;
            const int bslot = aslot + 1;

            bf16x8 af[8];
#pragma unroll
            for (int f = 0; f < 8; ++f) {
                int row = wm * 128 + f * 16 + lr;
                af[f] = *(const bf16x8*)&lds[aslot][row * 32 + rsw];
            }
            bf16x8 bfr[4];
#pragma unroll
            for (int f = 0; f < 4; ++f) {
                int row = wn * 64 + f * 16 + lr;
                bfr[f] = *(const bf16x8*)&lds[bslot][row * 32 + rsw];
            }

            {
                const int s0 = 8 * i + 2 * m + 6;
                if (s0 < 128) STAGE_HALF(s0, (2 * m + 6) & 7);
                if (s0 + 1 < 128) STAGE_HALF(s0 + 1, (2 * m + 7) & 7);
            }

            __builtin_amdgcn_s_barrier();

            __builtin_amdgcn_s_setprio(1);
#pragma unroll
            for (int f = 0; f < 8; ++f)
#pragma unroll
                for (int n = 0; n < 4; ++n)
                    acc[f][n] = __builtin_amdgcn_mfma_f32_16x16x32_bf16(
                        af[f], bfr[n], acc[f][n], 0, 0, 0);
            __builtin_amdgcn_s_setprio(0);

            // inline rowsum: wn==0 waves see each (row-frag, k-half) once
            if (wn == 0) {
#pragma unroll
                for (int f = 0; f < 8; ++f) {
                    union { bf16x8 v; unsigned u[4]; } cv;
                    cv.v = af[f];
#pragma unroll
                    for (int w = 0; w < 4; ++w)
                        rsm[f] += __uint_as_float(cv.u[w] << 16) +
                                  __uint_as_float(cv.u[w] & 0xffff0000u);
                }
            }

            if (sub == 1) {
                if (i == 15 && m == 1) asm volatile("s_waitcnt vmcnt(0)");
                else                   asm volatile("s_waitcnt vmcnt(4)");
            }
            __builtin_amdgcn_s_barrier();
        }
    }
#undef STAGE_HALF

    // rowsum: reduce across lg (lanes lr, lr+16, lr+32, lr+48)
    if (wn == 0) {
#pragma unroll
        for (int j = 0; j < 8; ++j) {
            rsm[j] += __shfl_xor(rsm[j], 16, 64);
            rsm[j] += __shfl_xor(rsm[j], 32, 64);
        }
        if (cx == 0 && lg == 0) {
            float* lp = lpart + (size_t)ks * 16384 + z * 4096 + row0 + wm * 128;
#pragma unroll
            for (int j = 0; j < 8; ++j) lp[j * 16 + lr] = rsm[j];
        }
    }

    float* O = part + (size_t)ks * 8388608 + ((size_t)z * 4096 + row0) * 512;
#pragma unroll
    for (int fm = 0; fm < 8; ++fm)
#pragma unroll
        for (int fn = 0; fn < 4; ++fn) {
            int c = col0 + wn * 64 + fn * 16 + lr;
#pragma unroll
            for (int reg = 0; reg < 4; ++reg) {
                int r = wm * 128 + fm * 16 + lg * 4 + reg;
                O[(size_t)r * 512 + c] = acc[fm][fn][reg];
            }
        }
}

// --------------------------- GEMM: C = A @ B^T (m97 128x128) ----------------
// EPI 1: bf16 TRANSPOSED store to vwT[batch][col][row&4095]  (vwT projection)
template <int EPI>
__launch_bounds__(256)
__global__ void gemm_bt_kernel(const u16* __restrict__ A, const u16* __restrict__ B,
                               void* __restrict__ Cout, int N, int K, int lda, int ldb,
                               long long sAz, long long sBz, long long sCz) {
    __shared__ u16 As[2][128 * 32];
    __shared__ u16 Bs[2][128 * 32];

    const int tid = threadIdx.x;
    const int wave = tid >> 6, lane = tid & 63;
    const int lr = lane & 15, lg = lane >> 4;
    const int wr = wave >> 1, wc = wave & 1;

    const int gx = gridDim.x, gy = gridDim.y;
    int bid = (blockIdx.z * gy + blockIdx.y) * gx + blockIdx.x;
    const int nwg = gx * gy * gridDim.z;
    int lgc = (bid & 7) * (nwg >> 3) + (bid >> 3);
    const int bx = lgc % gx;
    int rem = lgc / gx;
    const int by = rem % gy, z = rem / gy;
    const int row0 = by * 128, col0 = bx * 128;

    const u16* Ab = A + (size_t)z * sAz;
    const u16* Bb = B + (size_t)z * sBz;

    f32x4 acc[4][4];
#pragma unroll
    for (int i = 0; i < 4; ++i)
#pragma unroll
        for (int j = 0; j < 4; ++j) acc[i][j] = (f32x4){0.f, 0.f, 0.f, 0.f};

    const int KT = K >> 5;

#define STAGE(bufi, kt2)                                                          \
    {                                                                             \
        _Pragma("unroll") for (int i = 0; i < 2; ++i) {                           \
            int chunk = i * 256 + tid;                                            \
            int r = chunk >> 2, c4 = chunk & 3;                                   \
            load_lds16(Ab + (size_t)(row0 + r) * lda + (kt2) * 32 + c4 * 8,       \
                       &As[bufi][(i * 256 + wave * 64) * 8]);                     \
            load_lds16(Bb + (size_t)(col0 + r) * ldb + (kt2) * 32 + c4 * 8,       \
                       &Bs[bufi][(i * 256 + wave * 64) * 8]);                     \
        }                                                                         \
    }

    STAGE(0, 0);
    int buf = 0;
    for (int kt = 0; kt < KT; ++kt) {
        __syncthreads();
        if (kt + 1 < KT) STAGE(buf ^ 1, kt + 1);

        bf16x8 af[4], bfr[4];
#pragma unroll
        for (int mf = 0; mf < 4; ++mf)
            af[mf] = *(const bf16x8*)&As[buf][(wr * 64 + mf * 16 + lr) * 32 + lg * 8];
#pragma unroll
        for (int nf = 0; nf < 4; ++nf)
            bfr[nf] = *(const bf16x8*)&Bs[buf][(wc * 64 + nf * 16 + lr) * 32 + lg * 8];
#pragma unroll
        for (int mf = 0; mf < 4; ++mf)
#pragma unroll
            for (int nf = 0; nf < 4; ++nf)
                acc[mf][nf] = __builtin_amdgcn_mfma_f32_16x16x32_bf16(
                    af[mf], bfr[nf], acc[mf][nf], 0, 0, 0);
        buf ^= 1;
    }
#undef STAGE

    const int rbase = row0 + wr * 64;
    const int cbase = col0 + wc * 64;

    if (EPI == 0) {
        u16* C = (u16*)Cout + (size_t)z * sCz;
#pragma unroll
        for (int mf = 0; mf < 4; ++mf)
#pragma unroll
            for (int nf = 0; nf < 4; ++nf)
#pragma unroll
                for (int reg = 0; reg < 4; ++reg) {
                    int r = rbase + mf * 16 + lg * 4 + reg;
                    int c = cbase + nf * 16 + lr;
                    C[(size_t)r * N + c] = f2bf(acc[mf][nf][reg]);
                }
    } else {  // EPI == 1: transposed store vwT[batch][col][row%4096]
        u16* C = (u16*)Cout;
#pragma unroll
        for (int mf = 0; mf < 4; ++mf)
#pragma unroll
            for (int nf = 0; nf < 4; ++nf) {
                int rg = rbase + mf * 16 + lg * 4;
                int bsel = rg >> 12, rl = rg & 4095;
                int c = cbase + nf * 16 + lr;
                union { u16 u[4]; uint2 v; } o;
#pragma unroll
                for (int reg = 0; reg < 4; ++reg) o.u[reg] = f2bf(acc[mf][nf][reg]);
                *(uint2*)(C + ((size_t)bsel << 21) + ((size_t)c << 12) + rl) = o.v;
            }
    }
}

// --------------------------- reduce: out = (p0+p1)/l + bo -------------------
__global__ void reduce_kernel(const float* __restrict__ part,
                              const float* __restrict__ lpart,
                              const float* __restrict__ bo,
                              float* __restrict__ out) {
    int i = blockIdx.x * blockDim.x + threadIdx.x;
    int r = i >> 7, c4 = i & 127;
    float inv = 1.0f / (lpart[r] + lpart[16384 + r]);
    float4 a = ((const float4*)part)[i];
    float4 b = ((const float4*)part)[i + 2097152];
    float4 bi = ((const float4*)bo)[c4];
    float4 o;
    o.x = (a.x + b.x) * inv + bi.x;
    o.y = (a.y + b.y) * inv + bi.y;
    o.z = (a.z + b.z) * inv + bi.z;
    o.w = (a.w + b.w) * inv + bi.w;
    ((float4*)out)[i] = o;
}

// ---------------------------------------------------------------------------
extern "C" void kernel_launch(void* const* d_in, const int* in_sizes, int n_in,
                              void* d_out, int out_size, void* d_ws, size_t ws_size,
                              hipStream_t stream) {
    const float* x  = (const float*)d_in[0];
    const float* y  = (const float*)d_in[1];
    const float* Wq = (const float*)d_in[2];
    const float* Wk = (const float*)d_in[3];
    const float* Wv = (const float*)d_in[4];
    const float* Wo = (const float*)d_in[5];
    const float* bo = (const float*)d_in[6];
    float* out = (float*)d_out;

    char* ws = (char*)d_ws;
    u16*   xb   = (u16*)(ws + 0);            // 16 MB (16384 x 512); yb follows
    u16*   qk   = (u16*)(ws + 33554432);     // 32 MB (16384 x 1024: q|k)
    float* part = (float*)(ws + 0);          // 64 MB [2][16384][512] (reuses xb/yb/qk)
    u16*   vwT  = (u16*)(ws + 67108864);     // 16 MB [4][512][4096]
    u16*   Wqkb = (u16*)(ws + 83886080);     // 1 MB  (1024 x 512)
    u16*   Wvob = (u16*)(ws + 84934656);     // 512 KB
    float* lpart= (float*)(ws + 86507520);   // 128 KB [2][16384]
    u16*   P    = (u16*)(ws + 86638592);     // 128 MB [4][4096][4096]

    // 1) single prep launch: x/y -> bf16, [Wq*s|Wk] -> bf16, Wvo=Wo@Wv -> bf16
    prep_kernel<<<8576, 256, 0, stream>>>(x, y, Wq, Wk, Wo, Wv, xb, Wqkb, Wvob);

    // 2) projections: qk = xb @ Wqkb^T (8-phase 256^2) ; vwT = (yb @ Wvob^T)^T
    gemm256_kernel<0, 1><<<dim3(4, 64), 512, 0, stream>>>(xb, Wqkb, qk,
                                                          1024, 512, 512, 0, 0, 0);
    gemm_bt_kernel<1><<<dim3(4, 128, 1), 256, 0, stream>>>(xb + 8388608, Wvob, vwT,
                                                           512, 512, 512, 512, 0, 0, 0);

    // 3) P = exp(q @ k^T) — PERSISTENT 256 blocks x 4 batch-tiles
    gemm256_kernel<1, 4><<<dim3(16, 16), 512, 0, stream>>>(qk, qk + 512, P,
                                                           4096, 1024, 1024,
                                                           4194304, 4194304, 16777216);

    // 4) PV split-K partials + inline rowsum — merged-phase kernel
    pv8_kernel<<<256, 512, 0, stream>>>(P, vwT, part, lpart);

    // 5) out = (part0 + part1)/(l0 + l1) + bo
    reduce_kernel<<<8192, 256, 0, stream>>>(part, lpart, bo, out);
}

// Round 16
// 314.374 us; speedup vs baseline: 1.1973x; 1.1973x over previous
//
#include <hip/hip_runtime.h>
#include <hip/hip_bf16.h>

// ---------------------------------------------------------------------------
// Multihead attention (single 512-wide head), b=4, n=4096, d=inner=512, fp32 io.
//   qk = x@[Wq*s | Wk]^T   (merged projection, 8-phase 256^2 kernel)
//   vw = y@(Wo@Wv)^T       (out-proj folded into V), stored transposed as vwT
//   P  = exp(q@k^T)        (no max subtraction: |S| small, fp32-safe)
//   out = (P@vw)/rowsum(P) + bo   (split-K=2 PV + deterministic reduce)
// R16: gemm256 reverted to R14's measured codegen (persistent refactor
//      spilled acc to scratch: WRITE 131->289 MB); prep merge kept.
// ---------------------------------------------------------------------------

typedef unsigned short u16;
typedef __bf16 bf16x8 __attribute__((ext_vector_type(8)));
typedef float f32x4 __attribute__((ext_vector_type(4)));

#define SCALE_QK 0.044194173824159216f /* 1/sqrt(512) */

__device__ __forceinline__ u16 f2bf(float f) {
    __hip_bfloat16 h = __float2bfloat16(f);
    return __builtin_bit_cast(u16, h);
}

__device__ __forceinline__ void load_lds16(const void* g, void* l) {
    __builtin_amdgcn_global_load_lds(
        (const __attribute__((address_space(1))) void*)g,
        (__attribute__((address_space(3))) void*)l, 16, 0, 0);
}

// ---------------- prep: x/y -> bf16, [Wq*s|Wk] -> bf16, Wvo=Wo@Wv -> bf16 ---
__global__ void prep_kernel(const float* __restrict__ x, const float* __restrict__ y,
                            const float* __restrict__ Wq, const float* __restrict__ Wk,
                            const float* __restrict__ Wo, const float* __restrict__ Wv,
                            u16* __restrict__ xb, u16* __restrict__ Wqkb,
                            u16* __restrict__ Wvob) {
    const int b = blockIdx.x, tid = threadIdx.x;
    if (b < 8448) {
        const float *s0, *s1;
        u16* dst;
        int n8, i;
        float sc0, sc1;
        if (b < 8192) { s0 = x;  s1 = y;  dst = xb;   n8 = 1048576; sc0 = 1.f;      sc1 = 1.f; i = b * 256 + tid; }
        else          { s0 = Wq; s1 = Wk; dst = Wqkb; n8 = 32768;   sc0 = SCALE_QK; sc1 = 1.f; i = (b - 8192) * 256 + tid; }
        const float4* s4;
        float scale;
        int j;
        if (i < n8) { s4 = (const float4*)s0; scale = sc0; j = i; }
        else        { s4 = (const float4*)s1; scale = sc1; j = i - n8; }
        float4 v0 = s4[2 * j], v1 = s4[2 * j + 1];
        union { u16 u[8]; uint4 v; } o;
        o.u[0] = f2bf(v0.x * scale); o.u[1] = f2bf(v0.y * scale);
        o.u[2] = f2bf(v0.z * scale); o.u[3] = f2bf(v0.w * scale);
        o.u[4] = f2bf(v1.x * scale); o.u[5] = f2bf(v1.y * scale);
        o.u[6] = f2bf(v1.z * scale); o.u[7] = f2bf(v1.w * scale);
        ((uint4*)dst)[i] = o.v;
    } else {
        // Wvo = Wo @ Wv -> bf16, 4 rows per block (blocks 8448..8575)
        int ob = (b - 8448) * 4, t = tid;
        float a[4][2] = {{0.f, 0.f}, {0.f, 0.f}, {0.f, 0.f}, {0.f, 0.f}};
        for (int i = 0; i < 512; ++i) {
            float v0 = Wv[i * 512 + t], v1 = Wv[i * 512 + t + 256];
#pragma unroll
            for (int r = 0; r < 4; ++r) {
                float w = Wo[(ob + r) * 512 + i];
                a[r][0] += w * v0;
                a[r][1] += w * v1;
            }
        }
#pragma unroll
        for (int r = 0; r < 4; ++r) {
            Wvob[(ob + r) * 512 + t] = f2bf(a[r][0]);
            Wvob[(ob + r) * 512 + t + 256] = f2bf(a[r][1]);
        }
    }
}

// ===========================================================================
// 256x256 merged-phase GEMM, K=512:  C = (DOEXP ? exp : id)(A@B^T) -> bf16.
// 8 waves (2M x 4N), wave 128x64; 8 slots x 16KB; 32 MFMA per barrier pair.
// General grid decode (nwg % 8 == 0 bijective XCD swizzle).  (R14 codegen.)
// ===========================================================================
template <int DOEXP>
__launch_bounds__(512, 2)
__global__ void gemm256_kernel(const u16* __restrict__ A, const u16* __restrict__ B,
                               u16* __restrict__ Cout, int N, int lda, int ldb,
                               long long sAz, long long sBz, long long sCz) {
    __shared__ u16 lds[8][8192];

    const int tid = threadIdx.x;
    const int wave = tid >> 6, lane = tid & 63;
    const int lr = lane & 15, lg = lane >> 4;
    const int wm = wave >> 2, wn = wave & 3;
    const int rsw = (lg ^ ((lr >> 1) & 3)) << 3;  // read-side swizzled k-group*8

    const int gx = gridDim.x, gy = gridDim.y;
    int bid = (blockIdx.z * gy + blockIdx.y) * gx + blockIdx.x;
    const int nwg = gx * gy * gridDim.z;
    int lgc = (bid & 7) * (nwg >> 3) + (bid >> 3);
    const int bx = lgc % gx;
    int rem = lgc / gx;
    const int by = rem % gy, z = rem / gy;
    const int row0 = by * 256, col0 = bx * 256;

    const u16* Ab = A + (size_t)z * sAz;
    const u16* Bb = B + (size_t)z * sBz;

    const int rb = lane >> 2;
    const int kg8 = ((lane & 3) ^ ((rb >> 1) & 3)) << 3;  // stage-side swizzle

    f32x4 acc[8][4];
#pragma unroll
    for (int i = 0; i < 8; ++i)
#pragma unroll
        for (int j = 0; j < 4; ++j) acc[i][j] = (f32x4){0.f, 0.f, 0.f, 0.f};

#define STAGE_HALF(s_, slot_)                                                     \
    {                                                                             \
        const int h_ = (s_)&3, ts_ = (s_) >> 2;                                   \
        const u16* G_ = (h_ & 1) ? Bb : Ab;                                       \
        const int pan_ = (h_ & 1) ? col0 : row0;                                  \
        const int ld_ = (h_ & 1) ? ldb : lda;                                     \
        const int kofs_ = ts_ * 64 + (h_ >> 1) * 32 + kg8;                        \
        _Pragma("unroll") for (int j_ = 0; j_ < 2; ++j_) {                        \
            int r_ = (j_ * 8 + wave) * 16 + rb;                                   \
            load_lds16(G_ + (size_t)(pan_ + r_) * ld_ + kofs_,                    \
                       &lds[slot_][(j_ * 8 + wave) * 512]);                       \
        }                                                                         \
    }

    #pragma unroll
    for (int s = 0; s < 6; ++s) STAGE_HALF(s, s);
    asm volatile("s_waitcnt vmcnt(4)");
    __builtin_amdgcn_s_barrier();

#pragma unroll
    for (int i = 0; i < 4; ++i) {
#pragma unroll
        for (int m = 0; m < 4; ++m) {           // merged phase: global M = 4i+m
            const int sub = m & 1;              // k-half within tile
            const int tp = (m >> 1) & 1;        // tile parity
            const int aslot = tp * 4 + 2 * sub;
            const int bslot = aslot + 1;

            bf16x8 af[8];
#pragma unroll
            for (int f = 0; f < 8; ++f) {
                int row = wm * 128 + f * 16 + lr;
                af[f] = *(const bf16x8*)&lds[aslot][row * 32 + rsw];
            }
            bf16x8 bfr[4];
#pragma unroll
            for (int f = 0; f < 4; ++f) {
                int row = wn * 64 + f * 16 + lr;
                bfr[f] = *(const bf16x8*)&lds[bslot][row * 32 + rsw];
            }

            {
                const int s0 = 8 * i + 2 * m + 6;
                if (s0 < 32) STAGE_HALF(s0, (2 * m + 6) & 7);
                if (s0 + 1 < 32) STAGE_HALF(s0 + 1, (2 * m + 7) & 7);
            }

            __builtin_amdgcn_s_barrier();

            __builtin_amdgcn_s_setprio(1);
#pragma unroll
            for (int f = 0; f < 8; ++f)
#pragma unroll
                for (int n = 0; n < 4; ++n)
                    acc[f][n] = __builtin_amdgcn_mfma_f32_16x16x32_bf16(
                        af[f], bfr[n], acc[f][n], 0, 0, 0);
            __builtin_amdgcn_s_setprio(0);

            if (sub == 1) {
                if (i == 3 && m == 1) asm volatile("s_waitcnt vmcnt(0)");
                else                  asm volatile("s_waitcnt vmcnt(4)");
            }
            __builtin_amdgcn_s_barrier();
        }
    }
#undef STAGE_HALF

    u16* C = Cout + (size_t)z * sCz;
#pragma unroll
    for (int fm = 0; fm < 8; ++fm)
#pragma unroll
        for (int fn = 0; fn < 4; ++fn)
#pragma unroll
            for (int reg = 0; reg < 4; ++reg) {
                int r = row0 + wm * 128 + fm * 16 + lg * 4 + reg;
                int c = col0 + wn * 64 + fn * 16 + lr;
                float v = acc[fm][fn][reg];
                if (DOEXP) v = __expf(v);
                C[(size_t)r * N + c] = f2bf(v);
            }
}

// ===========================================================================
// 256x256 PV: part[ks] = P[:, ks-half] @ vw[ks-half], inline rowsum.
// 256 blocks (1/CU), 32 K-tiles = 64 merged phases. lda = ldb = 4096.
// ===========================================================================
__launch_bounds__(512, 2)
__global__ void pv8_kernel(const u16* __restrict__ P, const u16* __restrict__ vwT,
                           float* __restrict__ part, float* __restrict__ lpart) {
    __shared__ u16 lds[8][8192];

    const int tid = threadIdx.x;
    const int wave = tid >> 6, lane = tid & 63;
    const int lr = lane & 15, lg = lane >> 4;
    const int wm = wave >> 2, wn = wave & 3;
    const int rsw = (lg ^ ((lr >> 1) & 3)) << 3;

    int bid = blockIdx.x;
    int lgc = (bid & 7) * 32 + (bid >> 3);
    const int rp = lgc & 15;
    const int t5 = lgc >> 4;
    const int cx = t5 & 1, ks = (t5 >> 1) & 1, z = t5 >> 2;
    const int row0 = rp * 256;
    const int col0 = cx * 256;

    const u16* Ab = P + (size_t)z * 16777216 + (size_t)ks * 2048;
    const u16* Bb = vwT + (size_t)z * 2097152 + (size_t)ks * 2048;

    const int rb = lane >> 2;
    const int kg8 = ((lane & 3) ^ ((rb >> 1) & 3)) << 3;

    f32x4 acc[8][4];
#pragma unroll
    for (int i = 0; i < 8; ++i)
#pragma unroll
        for (int j = 0; j < 4; ++j) acc[i][j] = (f32x4){0.f, 0.f, 0.f, 0.f};
    float rsm[8] = {0.f, 0.f, 0.f, 0.f, 0.f, 0.f, 0.f, 0.f};

#define STAGE_HALF(s_, slot_)                                                     \
    {                                                                             \
        const int h_ = (s_)&3, ts_ = (s_) >> 2;                                   \
        const u16* G_ = (h_ & 1) ? Bb : Ab;                                       \
        const int pan_ = (h_ & 1) ? col0 : row0;                                  \
        const int kofs_ = ts_ * 64 + (h_ >> 1) * 32 + kg8;                        \
        _Pragma("unroll") for (int j_ = 0; j_ < 2; ++j_) {                        \
            int r_ = (j_ * 8 + wave) * 16 + rb;                                   \
            load_lds16(G_ + (size_t)(pan_ + r_) * 4096 + kofs_,                   \
                       &lds[slot_][(j_ * 8 + wave) * 512]);                       \
        }                                                                         \
    }

    #pragma unroll
    for (int s = 0; s < 6; ++s) STAGE_HALF(s, s);
    asm volatile("s_waitcnt vmcnt(4)");
    __builtin_amdgcn_s_barrier();

    for (int i = 0; i < 16; ++i) {
#pragma unroll
        for (int m = 0; m < 4; ++m) {           // merged phase
            const int sub = m & 1;
            const int tp = (m >> 1) & 1;
            const int aslot = tp * 4 + 2 * sub;
            const int bslot = aslot + 1;

            bf16x8 af[8];
#pragma unroll
            for (int f = 0; f < 8; ++f) {
                int row = wm * 128 + f * 16 + lr;
                af[f] = *(const bf16x8*)&lds[aslot][row * 32 + rsw];
            }
            bf16x8 bfr[4];
#pragma unroll
            for (int f = 0; f < 4; ++f) {
                int row = wn * 64 + f * 16 + lr;
                bfr[f] = *(const bf16x8*)&lds[bslot][row * 32 + rsw];
            }

            {
                const int s0 = 8 * i + 2 * m + 6;
                if (s0 < 128) STAGE_HALF(s0, (2 * m + 6) & 7);
                if (s0 + 1 < 128) STAGE_HALF(s0 + 1, (2 * m + 7) & 7);
            }

            __builtin_amdgcn_s_barrier();

            __builtin_amdgcn_s_setprio(1);
#pragma unroll
            for (int f = 0; f < 8; ++f)
#pragma unroll
                for (int n = 0; n < 4; ++n)
                    acc[f][n] = __builtin_amdgcn_mfma_f32_16x16x32_bf16(
                        af[f], bfr[n], acc[f][n], 0, 0, 0);
            __builtin_amdgcn_s_setprio(0);

            // inline rowsum: wn==0 waves see each (row-frag, k-half) once
            if (wn == 0) {
#pragma unroll
                for (int f = 0; f < 8; ++f) {
                    union { bf16x8 v; unsigned u[4]; } cv;
                    cv.v = af[f];
#pragma unroll
                    for (int w = 0; w < 4; ++w)
                        rsm[f] += __uint_as_float(cv.u[w] << 16) +
                                  __uint_as_float(cv.u[w] & 0xffff0000u);
                }
            }

            if (sub == 1) {
                if (i == 15 && m == 1) asm volatile("s_waitcnt vmcnt(0)");
                else                   asm volatile("s_waitcnt vmcnt(4)");
            }
            __builtin_amdgcn_s_barrier();
        }
    }
#undef STAGE_HALF

    // rowsum: reduce across lg (lanes lr, lr+16, lr+32, lr+48)
    if (wn == 0) {
#pragma unroll
        for (int j = 0; j < 8; ++j) {
            rsm[j] += __shfl_xor(rsm[j], 16, 64);
            rsm[j] += __shfl_xor(rsm[j], 32, 64);
        }
        if (cx == 0 && lg == 0) {
            float* lp = lpart + (size_t)ks * 16384 + z * 4096 + row0 + wm * 128;
#pragma unroll
            for (int j = 0; j < 8; ++j) lp[j * 16 + lr] = rsm[j];
        }
    }

    float* O = part + (size_t)ks * 8388608 + ((size_t)z * 4096 + row0) * 512;
#pragma unroll
    for (int fm = 0; fm < 8; ++fm)
#pragma unroll
        for (int fn = 0; fn < 4; ++fn) {
            int c = col0 + wn * 64 + fn * 16 + lr;
#pragma unroll
            for (int reg = 0; reg < 4; ++reg) {
                int r = wm * 128 + fm * 16 + lg * 4 + reg;
                O[(size_t)r * 512 + c] = acc[fm][fn][reg];
            }
        }
}

// --------------------------- GEMM: C = A @ B^T (m97 128x128) ----------------
// EPI 1: bf16 TRANSPOSED store to vwT[batch][col][row&4095]  (vwT projection)
template <int EPI>
__launch_bounds__(256)
__global__ void gemm_bt_kernel(const u16* __restrict__ A, const u16* __restrict__ B,
                               void* __restrict__ Cout, int N, int K, int lda, int ldb,
                               long long sAz, long long sBz, long long sCz) {
    __shared__ u16 As[2][128 * 32];
    __shared__ u16 Bs[2][128 * 32];

    const int tid = threadIdx.x;
    const int wave = tid >> 6, lane = tid & 63;
    const int lr = lane & 15, lg = lane >> 4;
    const int wr = wave >> 1, wc = wave & 1;

    const int gx = gridDim.x, gy = gridDim.y;
    int bid = (blockIdx.z * gy + blockIdx.y) * gx + blockIdx.x;
    const int nwg = gx * gy * gridDim.z;
    int lgc = (bid & 7) * (nwg >> 3) + (bid >> 3);
    const int bx = lgc % gx;
    int rem = lgc / gx;
    const int by = rem % gy, z = rem / gy;
    const int row0 = by * 128, col0 = bx * 128;

    const u16* Ab = A + (size_t)z * sAz;
    const u16* Bb = B + (size_t)z * sBz;

    f32x4 acc[4][4];
#pragma unroll
    for (int i = 0; i < 4; ++i)
#pragma unroll
        for (int j = 0; j < 4; ++j) acc[i][j] = (f32x4){0.f, 0.f, 0.f, 0.f};

    const int KT = K >> 5;

#define STAGE(bufi, kt2)                                                          \
    {                                                                             \
        _Pragma("unroll") for (int i = 0; i < 2; ++i) {                           \
            int chunk = i * 256 + tid;                                            \
            int r = chunk >> 2, c4 = chunk & 3;                                   \
            load_lds16(Ab + (size_t)(row0 + r) * lda + (kt2) * 32 + c4 * 8,       \
                       &As[bufi][(i * 256 + wave * 64) * 8]);                     \
            load_lds16(Bb + (size_t)(col0 + r) * ldb + (kt2) * 32 + c4 * 8,       \
                       &Bs[bufi][(i * 256 + wave * 64) * 8]);                     \
        }                                                                         \
    }

    STAGE(0, 0);
    int buf = 0;
    for (int kt = 0; kt < KT; ++kt) {
        __syncthreads();
        if (kt + 1 < KT) STAGE(buf ^ 1, kt + 1);

        bf16x8 af[4], bfr[4];
#pragma unroll
        for (int mf = 0; mf < 4; ++mf)
            af[mf] = *(const bf16x8*)&As[buf][(wr * 64 + mf * 16 + lr) * 32 + lg * 8];
#pragma unroll
        for (int nf = 0; nf < 4; ++nf)
            bfr[nf] = *(const bf16x8*)&Bs[buf][(wc * 64 + nf * 16 + lr) * 32 + lg * 8];
#pragma unroll
        for (int mf = 0; mf < 4; ++mf)
#pragma unroll
            for (int nf = 0; nf < 4; ++nf)
                acc[mf][nf] = __builtin_amdgcn_mfma_f32_16x16x32_bf16(
                    af[mf], bfr[nf], acc[mf][nf], 0, 0, 0);
        buf ^= 1;
    }
#undef STAGE

    const int rbase = row0 + wr * 64;
    const int cbase = col0 + wc * 64;

    if (EPI == 0) {
        u16* C = (u16*)Cout + (size_t)z * sCz;
#pragma unroll
        for (int mf = 0; mf < 4; ++mf)
#pragma unroll
            for (int nf = 0; nf < 4; ++nf)
#pragma unroll
                for (int reg = 0; reg < 4; ++reg) {
                    int r = rbase + mf * 16 + lg * 4 + reg;
                    int c = cbase + nf * 16 + lr;
                    C[(size_t)r * N + c] = f2bf(acc[mf][nf][reg]);
                }
    } else {  // EPI == 1: transposed store vwT[batch][col][row%4096]
        u16* C = (u16*)Cout;
#pragma unroll
        for (int mf = 0; mf < 4; ++mf)
#pragma unroll
            for (int nf = 0; nf < 4; ++nf) {
                int rg = rbase + mf * 16 + lg * 4;
                int bsel = rg >> 12, rl = rg & 4095;
                int c = cbase + nf * 16 + lr;
                union { u16 u[4]; uint2 v; } o;
#pragma unroll
                for (int reg = 0; reg < 4; ++reg) o.u[reg] = f2bf(acc[mf][nf][reg]);
                *(uint2*)(C + ((size_t)bsel << 21) + ((size_t)c << 12) + rl) = o.v;
            }
    }
}

// --------------------------- reduce: out = (p0+p1)/l + bo -------------------
__global__ void reduce_kernel(const float* __restrict__ part,
                              const float* __restrict__ lpart,
                              const float* __restrict__ bo,
                              float* __restrict__ out) {
    int i = blockIdx.x * blockDim.x + threadIdx.x;
    int r = i >> 7, c4 = i & 127;
    float inv = 1.0f / (lpart[r] + lpart[16384 + r]);
    float4 a = ((const float4*)part)[i];
    float4 b = ((const float4*)part)[i + 2097152];
    float4 bi = ((const float4*)bo)[c4];
    float4 o;
    o.x = (a.x + b.x) * inv + bi.x;
    o.y = (a.y + b.y) * inv + bi.y;
    o.z = (a.z + b.z) * inv + bi.z;
    o.w = (a.w + b.w) * inv + bi.w;
    ((float4*)out)[i] = o;
}

// ---------------------------------------------------------------------------
extern "C" void kernel_launch(void* const* d_in, const int* in_sizes, int n_in,
                              void* d_out, int out_size, void* d_ws, size_t ws_size,
                              hipStream_t stream) {
    const float* x  = (const float*)d_in[0];
    const float* y  = (const float*)d_in[1];
    const float* Wq = (const float*)d_in[2];
    const float* Wk = (const float*)d_in[3];
    const float* Wv = (const float*)d_in[4];
    const float* Wo = (const float*)d_in[5];
    const float* bo = (const float*)d_in[6];
    float* out = (float*)d_out;

    char* ws = (char*)d_ws;
    u16*   xb   = (u16*)(ws + 0);            // 16 MB (16384 x 512); yb follows
    u16*   qk   = (u16*)(ws + 33554432);     // 32 MB (16384 x 1024: q|k)
    float* part = (float*)(ws + 0);          // 64 MB [2][16384][512] (reuses xb/yb/qk)
    u16*   vwT  = (u16*)(ws + 67108864);     // 16 MB [4][512][4096]
    u16*   Wqkb = (u16*)(ws + 83886080);     // 1 MB  (1024 x 512)
    u16*   Wvob = (u16*)(ws + 84934656);     // 512 KB
    float* lpart= (float*)(ws + 86507520);   // 128 KB [2][16384]
    u16*   P    = (u16*)(ws + 86638592);     // 128 MB [4][4096][4096]

    // 1) single prep launch: x/y -> bf16, [Wq*s|Wk] -> bf16, Wvo=Wo@Wv -> bf16
    prep_kernel<<<8576, 256, 0, stream>>>(x, y, Wq, Wk, Wo, Wv, xb, Wqkb, Wvob);

    // 2) projections: qk = xb @ Wqkb^T (8-phase 256^2) ; vwT = (yb @ Wvob^T)^T
    gemm256_kernel<0><<<dim3(4, 64, 1), 512, 0, stream>>>(xb, Wqkb, qk,
                                                          1024, 512, 512, 0, 0, 0);
    gemm_bt_kernel<1><<<dim3(4, 128, 1), 256, 0, stream>>>(xb + 8388608, Wvob, vwT,
                                                           512, 512, 512, 512, 0, 0, 0);

    // 3) P = exp(q @ k^T) per batch — 256x256 merged-phase kernel
    gemm256_kernel<1><<<dim3(16, 16, 4), 512, 0, stream>>>(qk, qk + 512, P,
                                                           4096, 1024, 1024,
                                                           4194304, 4194304, 16777216);

    // 4) PV split-K partials + inline rowsum — merged-phase kernel
    pv8_kernel<<<256, 512, 0, stream>>>(P, vwT, part, lpart);

    // 5) out = (part0 + part1)/(l0 + l1) + bo
    reduce_kernel<<<8192, 256, 0, stream>>>(part, lpart, bo, out);
}

// Round 17
// 310.006 us; speedup vs baseline: 1.2141x; 1.0141x over previous
//
#include <hip/hip_runtime.h>
#include <hip/hip_bf16.h>

// ---------------------------------------------------------------------------
// Multihead attention (single 512-wide head), b=4, n=4096, d=inner=512, fp32 io.
//   qk = x@[Wq*s | Wk]^T   (merged projection, 8-phase 256^2 kernel)
//   vw = y@(Wo@Wv)^T       (out-proj folded into V), stored transposed as vwT
//   P  = exp(q@k^T)        (no max subtraction: |S| small, fp32-safe)
//   out = (P@vw)/rowsum(P) + bo   (split-K=2 PV + deterministic reduce)
// R17: S-GEMM block swizzle re-grouped for L2 locality — each XCD's 32
//      concurrent blocks = 4bx x 8by (3 MB working set <= 4 MB L2, vs 4.5 MB
//      linear decode). Decode-only change; inner loop codegen untouched.
// ---------------------------------------------------------------------------

typedef unsigned short u16;
typedef __bf16 bf16x8 __attribute__((ext_vector_type(8)));
typedef float f32x4 __attribute__((ext_vector_type(4)));

#define SCALE_QK 0.044194173824159216f /* 1/sqrt(512) */

__device__ __forceinline__ u16 f2bf(float f) {
    __hip_bfloat16 h = __float2bfloat16(f);
    return __builtin_bit_cast(u16, h);
}

__device__ __forceinline__ void load_lds16(const void* g, void* l) {
    __builtin_amdgcn_global_load_lds(
        (const __attribute__((address_space(1))) void*)g,
        (__attribute__((address_space(3))) void*)l, 16, 0, 0);
}

// ---------------- prep: x/y -> bf16, [Wq*s|Wk] -> bf16, Wvo=Wo@Wv -> bf16 ---
__global__ void prep_kernel(const float* __restrict__ x, const float* __restrict__ y,
                            const float* __restrict__ Wq, const float* __restrict__ Wk,
                            const float* __restrict__ Wo, const float* __restrict__ Wv,
                            u16* __restrict__ xb, u16* __restrict__ Wqkb,
                            u16* __restrict__ Wvob) {
    const int b = blockIdx.x, tid = threadIdx.x;
    if (b < 8448) {
        const float *s0, *s1;
        u16* dst;
        int n8, i;
        float sc0, sc1;
        if (b < 8192) { s0 = x;  s1 = y;  dst = xb;   n8 = 1048576; sc0 = 1.f;      sc1 = 1.f; i = b * 256 + tid; }
        else          { s0 = Wq; s1 = Wk; dst = Wqkb; n8 = 32768;   sc0 = SCALE_QK; sc1 = 1.f; i = (b - 8192) * 256 + tid; }
        const float4* s4;
        float scale;
        int j;
        if (i < n8) { s4 = (const float4*)s0; scale = sc0; j = i; }
        else        { s4 = (const float4*)s1; scale = sc1; j = i - n8; }
        float4 v0 = s4[2 * j], v1 = s4[2 * j + 1];
        union { u16 u[8]; uint4 v; } o;
        o.u[0] = f2bf(v0.x * scale); o.u[1] = f2bf(v0.y * scale);
        o.u[2] = f2bf(v0.z * scale); o.u[3] = f2bf(v0.w * scale);
        o.u[4] = f2bf(v1.x * scale); o.u[5] = f2bf(v1.y * scale);
        o.u[6] = f2bf(v1.z * scale); o.u[7] = f2bf(v1.w * scale);
        ((uint4*)dst)[i] = o.v;
    } else {
        // Wvo = Wo @ Wv -> bf16, 4 rows per block (blocks 8448..8575)
        int ob = (b - 8448) * 4, t = tid;
        float a[4][2] = {{0.f, 0.f}, {0.f, 0.f}, {0.f, 0.f}, {0.f, 0.f}};
        for (int i = 0; i < 512; ++i) {
            float v0 = Wv[i * 512 + t], v1 = Wv[i * 512 + t + 256];
#pragma unroll
            for (int r = 0; r < 4; ++r) {
                float w = Wo[(ob + r) * 512 + i];
                a[r][0] += w * v0;
                a[r][1] += w * v1;
            }
        }
#pragma unroll
        for (int r = 0; r < 4; ++r) {
            Wvob[(ob + r) * 512 + t] = f2bf(a[r][0]);
            Wvob[(ob + r) * 512 + t + 256] = f2bf(a[r][1]);
        }
    }
}

// ===========================================================================
// 256x256 merged-phase GEMM, K=512:  C = (DOEXP ? exp : id)(A@B^T) -> bf16.
// 8 waves (2M x 4N), wave 128x64; 8 slots x 16KB; 32 MFMA per barrier pair.
// GROUPED=0: linear decode (general nwg%8==0).  GROUPED=1: grid must be
// (16,16,4); each XCD chunk of 128 lgc decodes as 4 groups of 32 = 4bx x 8by
// so the 32 concurrent blocks fit A(2MB)+B(1MB) in the XCD L2.
// ===========================================================================
template <int DOEXP, int GROUPED>
__launch_bounds__(512, 2)
__global__ void gemm256_kernel(const u16* __restrict__ A, const u16* __restrict__ B,
                               u16* __restrict__ Cout, int N, int lda, int ldb,
                               long long sAz, long long sBz, long long sCz) {
    __shared__ u16 lds[8][8192];

    const int tid = threadIdx.x;
    const int wave = tid >> 6, lane = tid & 63;
    const int lr = lane & 15, lg = lane >> 4;
    const int wm = wave >> 2, wn = wave & 3;
    const int rsw = (lg ^ ((lr >> 1) & 3)) << 3;  // read-side swizzled k-group*8

    const int gx = gridDim.x, gy = gridDim.y;
    int bid = (blockIdx.z * gy + blockIdx.y) * gx + blockIdx.x;
    const int nwg = gx * gy * gridDim.z;
    int lgc = (bid & 7) * (nwg >> 3) + (bid >> 3);
    int bx, by, z;
    if (GROUPED) {
        // grid (16,16,4): z = lgc>>8; r = lgc&255; group g = r>>5 (32 blocks):
        // bx = (g&3)*4 + (loc&3), by = (g>>2)*8 + (loc>>2)   [bijective]
        z = lgc >> 8;
        int r = lgc & 255;
        int g = r >> 5, loc = r & 31;
        bx = (g & 3) * 4 + (loc & 3);
        by = (g >> 2) * 8 + (loc >> 2);
    } else {
        bx = lgc % gx;
        int rem = lgc / gx;
        by = rem % gy;
        z = rem / gy;
    }
    const int row0 = by * 256, col0 = bx * 256;

    const u16* Ab = A + (size_t)z * sAz;
    const u16* Bb = B + (size_t)z * sBz;

    const int rb = lane >> 2;
    const int kg8 = ((lane & 3) ^ ((rb >> 1) & 3)) << 3;  // stage-side swizzle

    f32x4 acc[8][4];
#pragma unroll
    for (int i = 0; i < 8; ++i)
#pragma unroll
        for (int j = 0; j < 4; ++j) acc[i][j] = (f32x4){0.f, 0.f, 0.f, 0.f};

#define STAGE_HALF(s_, slot_)                                                     \
    {                                                                             \
        const int h_ = (s_)&3, ts_ = (s_) >> 2;                                   \
        const u16* G_ = (h_ & 1) ? Bb : Ab;                                       \
        const int pan_ = (h_ & 1) ? col0 : row0;                                  \
        const int ld_ = (h_ & 1) ? ldb : lda;                                     \
        const int kofs_ = ts_ * 64 + (h_ >> 1) * 32 + kg8;                        \
        _Pragma("unroll") for (int j_ = 0; j_ < 2; ++j_) {                        \
            int r_ = (j_ * 8 + wave) * 16 + rb;                                   \
            load_lds16(G_ + (size_t)(pan_ + r_) * ld_ + kofs_,                    \
                       &lds[slot_][(j_ * 8 + wave) * 512]);                       \
        }                                                                         \
    }

    #pragma unroll
    for (int s = 0; s < 6; ++s) STAGE_HALF(s, s);
    asm volatile("s_waitcnt vmcnt(4)");
    __builtin_amdgcn_s_barrier();

#pragma unroll
    for (int i = 0; i < 4; ++i) {
#pragma unroll
        for (int m = 0; m < 4; ++m) {           // merged phase: global M = 4i+m
            const int sub = m & 1;              // k-half within tile
            const int tp = (m >> 1) & 1;        // tile parity
            const int aslot = tp * 4 + 2 * sub;
            const int bslot = aslot + 1;

            bf16x8 af[8];
#pragma unroll
            for (int f = 0; f < 8; ++f) {
                int row = wm * 128 + f * 16 + lr;
                af[f] = *(const bf16x8*)&lds[aslot][row * 32 + rsw];
            }
            bf16x8 bfr[4];
#pragma unroll
            for (int f = 0; f < 4; ++f) {
                int row = wn * 64 + f * 16 + lr;
                bfr[f] = *(const bf16x8*)&lds[bslot][row * 32 + rsw];
            }

            {
                const int s0 = 8 * i + 2 * m + 6;
                if (s0 < 32) STAGE_HALF(s0, (2 * m + 6) & 7);
                if (s0 + 1 < 32) STAGE_HALF(s0 + 1, (2 * m + 7) & 7);
            }

            __builtin_amdgcn_s_barrier();

            __builtin_amdgcn_s_setprio(1);
#pragma unroll
            for (int f = 0; f < 8; ++f)
#pragma unroll
                for (int n = 0; n < 4; ++n)
                    acc[f][n] = __builtin_amdgcn_mfma_f32_16x16x32_bf16(
                        af[f], bfr[n], acc[f][n], 0, 0, 0);
            __builtin_amdgcn_s_setprio(0);

            if (sub == 1) {
                if (i == 3 && m == 1) asm volatile("s_waitcnt vmcnt(0)");
                else                  asm volatile("s_waitcnt vmcnt(4)");
            }
            __builtin_amdgcn_s_barrier();
        }
    }
#undef STAGE_HALF

    u16* C = Cout + (size_t)z * sCz;
#pragma unroll
    for (int fm = 0; fm < 8; ++fm)
#pragma unroll
        for (int fn = 0; fn < 4; ++fn)
#pragma unroll
            for (int reg = 0; reg < 4; ++reg) {
                int r = row0 + wm * 128 + fm * 16 + lg * 4 + reg;
                int c = col0 + wn * 64 + fn * 16 + lr;
                float v = acc[fm][fn][reg];
                if (DOEXP) v = __expf(v);
                C[(size_t)r * N + c] = f2bf(v);
            }
}

// ===========================================================================
// 256x256 PV: part[ks] = P[:, ks-half] @ vw[ks-half], inline rowsum.
// 256 blocks (1/CU), 32 K-tiles = 64 merged phases. lda = ldb = 4096.
// ===========================================================================
__launch_bounds__(512, 2)
__global__ void pv8_kernel(const u16* __restrict__ P, const u16* __restrict__ vwT,
                           float* __restrict__ part, float* __restrict__ lpart) {
    __shared__ u16 lds[8][8192];

    const int tid = threadIdx.x;
    const int wave = tid >> 6, lane = tid & 63;
    const int lr = lane & 15, lg = lane >> 4;
    const int wm = wave >> 2, wn = wave & 3;
    const int rsw = (lg ^ ((lr >> 1) & 3)) << 3;

    int bid = blockIdx.x;
    int lgc = (bid & 7) * 32 + (bid >> 3);
    const int rp = lgc & 15;
    const int t5 = lgc >> 4;
    const int cx = t5 & 1, ks = (t5 >> 1) & 1, z = t5 >> 2;
    const int row0 = rp * 256;
    const int col0 = cx * 256;

    const u16* Ab = P + (size_t)z * 16777216 + (size_t)ks * 2048;
    const u16* Bb = vwT + (size_t)z * 2097152 + (size_t)ks * 2048;

    const int rb = lane >> 2;
    const int kg8 = ((lane & 3) ^ ((rb >> 1) & 3)) << 3;

    f32x4 acc[8][4];
#pragma unroll
    for (int i = 0; i < 8; ++i)
#pragma unroll
        for (int j = 0; j < 4; ++j) acc[i][j] = (f32x4){0.f, 0.f, 0.f, 0.f};
    float rsm[8] = {0.f, 0.f, 0.f, 0.f, 0.f, 0.f, 0.f, 0.f};

#define STAGE_HALF(s_, slot_)                                                     \
    {                                                                             \
        const int h_ = (s_)&3, ts_ = (s_) >> 2;                                   \
        const u16* G_ = (h_ & 1) ? Bb : Ab;                                       \
        const int pan_ = (h_ & 1) ? col0 : row0;                                  \
        const int kofs_ = ts_ * 64 + (h_ >> 1) * 32 + kg8;                        \
        _Pragma("unroll") for (int j_ = 0; j_ < 2; ++j_) {                        \
            int r_ = (j_ * 8 + wave) * 16 + rb;                                   \
            load_lds16(G_ + (size_t)(pan_ + r_) * 4096 + kofs_,                   \
                       &lds[slot_][(j_ * 8 + wave) * 512]);                       \
        }                                                                         \
    }

    #pragma unroll
    for (int s = 0; s < 6; ++s) STAGE_HALF(s, s);
    asm volatile("s_waitcnt vmcnt(4)");
    __builtin_amdgcn_s_barrier();

    for (int i = 0; i < 16; ++i) {
#pragma unroll
        for (int m = 0; m < 4; ++m) {           // merged phase
            const int sub = m & 1;
            const int tp = (m >> 1) & 1;
            const int aslot = tp * 4 + 2 * sub;
            const int bslot = aslot + 1;

            bf16x8 af[8];
#pragma unroll
            for (int f = 0; f < 8; ++f) {
                int row = wm * 128 + f * 16 + lr;
                af[f] = *(const bf16x8*)&lds[aslot][row * 32 + rsw];
            }
            bf16x8 bfr[4];
#pragma unroll
            for (int f = 0; f < 4; ++f) {
                int row = wn * 64 + f * 16 + lr;
                bfr[f] = *(const bf16x8*)&lds[bslot][row * 32 + rsw];
            }

            {
                const int s0 = 8 * i + 2 * m + 6;
                if (s0 < 128) STAGE_HALF(s0, (2 * m + 6) & 7);
                if (s0 + 1 < 128) STAGE_HALF(s0 + 1, (2 * m + 7) & 7);
            }

            __builtin_amdgcn_s_barrier();

            __builtin_amdgcn_s_setprio(1);
#pragma unroll
            for (int f = 0; f < 8; ++f)
#pragma unroll
                for (int n = 0; n < 4; ++n)
                    acc[f][n] = __builtin_amdgcn_mfma_f32_16x16x32_bf16(
                        af[f], bfr[n], acc[f][n], 0, 0, 0);
            __builtin_amdgcn_s_setprio(0);

            // inline rowsum: wn==0 waves see each (row-frag, k-half) once
            if (wn == 0) {
#pragma unroll
                for (int f = 0; f < 8; ++f) {
                    union { bf16x8 v; unsigned u[4]; } cv;
                    cv.v = af[f];
#pragma unroll
                    for (int w = 0; w < 4; ++w)
                        rsm[f] += __uint_as_float(cv.u[w] << 16) +
                                  __uint_as_float(cv.u[w] & 0xffff0000u);
                }
            }

            if (sub == 1) {
                if (i == 15 && m == 1) asm volatile("s_waitcnt vmcnt(0)");
                else                   asm volatile("s_waitcnt vmcnt(4)");
            }
            __builtin_amdgcn_s_barrier();
        }
    }
#undef STAGE_HALF

    // rowsum: reduce across lg (lanes lr, lr+16, lr+32, lr+48)
    if (wn == 0) {
#pragma unroll
        for (int j = 0; j < 8; ++j) {
            rsm[j] += __shfl_xor(rsm[j], 16, 64);
            rsm[j] += __shfl_xor(rsm[j], 32, 64);
        }
        if (cx == 0 && lg == 0) {
            float* lp = lpart + (size_t)ks * 16384 + z * 4096 + row0 + wm * 128;
#pragma unroll
            for (int j = 0; j < 8; ++j) lp[j * 16 + lr] = rsm[j];
        }
    }

    float* O = part + (size_t)ks * 8388608 + ((size_t)z * 4096 + row0) * 512;
#pragma unroll
    for (int fm = 0; fm < 8; ++fm)
#pragma unroll
        for (int fn = 0; fn < 4; ++fn) {
            int c = col0 + wn * 64 + fn * 16 + lr;
#pragma unroll
            for (int reg = 0; reg < 4; ++reg) {
                int r = wm * 128 + fm * 16 + lg * 4 + reg;
                O[(size_t)r * 512 + c] = acc[fm][fn][reg];
            }
        }
}

// --------------------------- GEMM: C = A @ B^T (m97 128x128) ----------------
// EPI 1: bf16 TRANSPOSED store to vwT[batch][col][row&4095]  (vwT projection)
template <int EPI>
__launch_bounds__(256)
__global__ void gemm_bt_kernel(const u16* __restrict__ A, const u16* __restrict__ B,
                               void* __restrict__ Cout, int N, int K, int lda, int ldb,
                               long long sAz, long long sBz, long long sCz) {
    __shared__ u16 As[2][128 * 32];
    __shared__ u16 Bs[2][128 * 32];

    const int tid = threadIdx.x;
    const int wave = tid >> 6, lane = tid & 63;
    const int lr = lane & 15, lg = lane >> 4;
    const int wr = wave >> 1, wc = wave & 1;

    const int gx = gridDim.x, gy = gridDim.y;
    int bid = (blockIdx.z * gy + blockIdx.y) * gx + blockIdx.x;
    const int nwg = gx * gy * gridDim.z;
    int lgc = (bid & 7) * (nwg >> 3) + (bid >> 3);
    const int bx = lgc % gx;
    int rem = lgc / gx;
    const int by = rem % gy, z = rem / gy;
    const int row0 = by * 128, col0 = bx * 128;

    const u16* Ab = A + (size_t)z * sAz;
    const u16* Bb = B + (size_t)z * sBz;

    f32x4 acc[4][4];
#pragma unroll
    for (int i = 0; i < 4; ++i)
#pragma unroll
        for (int j = 0; j < 4; ++j) acc[i][j] = (f32x4){0.f, 0.f, 0.f, 0.f};

    const int KT = K >> 5;

#define STAGE(bufi, kt2)                                                          \
    {                                                                             \
        _Pragma("unroll") for (int i = 0; i < 2; ++i) {                           \
            int chunk = i * 256 + tid;                                            \
            int r = chunk >> 2, c4 = chunk & 3;                                   \
            load_lds16(Ab + (size_t)(row0 + r) * lda + (kt2) * 32 + c4 * 8,       \
                       &As[bufi][(i * 256 + wave * 64) * 8]);                     \
            load_lds16(Bb + (size_t)(col0 + r) * ldb + (kt2) * 32 + c4 * 8,       \
                       &Bs[bufi][(i * 256 + wave * 64) * 8]);                     \
        }                                                                         \
    }

    STAGE(0, 0);
    int buf = 0;
    for (int kt = 0; kt < KT; ++kt) {
        __syncthreads();
        if (kt + 1 < KT) STAGE(buf ^ 1, kt + 1);

        bf16x8 af[4], bfr[4];
#pragma unroll
        for (int mf = 0; mf < 4; ++mf)
            af[mf] = *(const bf16x8*)&As[buf][(wr * 64 + mf * 16 + lr) * 32 + lg * 8];
#pragma unroll
        for (int nf = 0; nf < 4; ++nf)
            bfr[nf] = *(const bf16x8*)&Bs[buf][(wc * 64 + nf * 16 + lr) * 32 + lg * 8];
#pragma unroll
        for (int mf = 0; mf < 4; ++mf)
#pragma unroll
            for (int nf = 0; nf < 4; ++nf)
                acc[mf][nf] = __builtin_amdgcn_mfma_f32_16x16x32_bf16(
                    af[mf], bfr[nf], acc[mf][nf], 0, 0, 0);
        buf ^= 1;
    }
#undef STAGE

    const int rbase = row0 + wr * 64;
    const int cbase = col0 + wc * 64;

    if (EPI == 0) {
        u16* C = (u16*)Cout + (size_t)z * sCz;
#pragma unroll
        for (int mf = 0; mf < 4; ++mf)
#pragma unroll
            for (int nf = 0; nf < 4; ++nf)
#pragma unroll
                for (int reg = 0; reg < 4; ++reg) {
                    int r = rbase + mf * 16 + lg * 4 + reg;
                    int c = cbase + nf * 16 + lr;
                    C[(size_t)r * N + c] = f2bf(acc[mf][nf][reg]);
                }
    } else {  // EPI == 1: transposed store vwT[batch][col][row%4096]
        u16* C = (u16*)Cout;
#pragma unroll
        for (int mf = 0; mf < 4; ++mf)
#pragma unroll
            for (int nf = 0; nf < 4; ++nf) {
                int rg = rbase + mf * 16 + lg * 4;
                int bsel = rg >> 12, rl = rg & 4095;
                int c = cbase + nf * 16 + lr;
                union { u16 u[4]; uint2 v; } o;
#pragma unroll
                for (int reg = 0; reg < 4; ++reg) o.u[reg] = f2bf(acc[mf][nf][reg]);
                *(uint2*)(C + ((size_t)bsel << 21) + ((size_t)c << 12) + rl) = o.v;
            }
    }
}

// --------------------------- reduce: out = (p0+p1)/l + bo -------------------
__global__ void reduce_kernel(const float* __restrict__ part,
                              const float* __restrict__ lpart,
                              const float* __restrict__ bo,
                              float* __restrict__ out) {
    int i = blockIdx.x * blockDim.x + threadIdx.x;
    int r = i >> 7, c4 = i & 127;
    float inv = 1.0f / (lpart[r] + lpart[16384 + r]);
    float4 a = ((const float4*)part)[i];
    float4 b = ((const float4*)part)[i + 2097152];
    float4 bi = ((const float4*)bo)[c4];
    float4 o;
    o.x = (a.x + b.x) * inv + bi.x;
    o.y = (a.y + b.y) * inv + bi.y;
    o.z = (a.z + b.z) * inv + bi.z;
    o.w = (a.w + b.w) * inv + bi.w;
    ((float4*)out)[i] = o;
}

// ---------------------------------------------------------------------------
extern "C" void kernel_launch(void* const* d_in, const int* in_sizes, int n_in,
                              void* d_out, int out_size, void* d_ws, size_t ws_size,
                              hipStream_t stream) {
    const float* x  = (const float*)d_in[0];
    const float* y  = (const float*)d_in[1];
    const float* Wq = (const float*)d_in[2];
    const float* Wk = (const float*)d_in[3];
    const float* Wv = (const float*)d_in[4];
    const float* Wo = (const float*)d_in[5];
    const float* bo = (const float*)d_in[6];
    float* out = (float*)d_out;

    char* ws = (char*)d_ws;
    u16*   xb   = (u16*)(ws + 0);            // 16 MB (16384 x 512); yb follows
    u16*   qk   = (u16*)(ws + 33554432);     // 32 MB (16384 x 1024: q|k)
    float* part = (float*)(ws + 0);          // 64 MB [2][16384][512] (reuses xb/yb/qk)
    u16*   vwT  = (u16*)(ws + 67108864);     // 16 MB [4][512][4096]
    u16*   Wqkb = (u16*)(ws + 83886080);     // 1 MB  (1024 x 512)
    u16*   Wvob = (u16*)(ws + 84934656);     // 512 KB
    float* lpart= (float*)(ws + 86507520);   // 128 KB [2][16384]
    u16*   P    = (u16*)(ws + 86638592);     // 128 MB [4][4096][4096]

    // 1) single prep launch: x/y -> bf16, [Wq*s|Wk] -> bf16, Wvo=Wo@Wv -> bf16
    prep_kernel<<<8576, 256, 0, stream>>>(x, y, Wq, Wk, Wo, Wv, xb, Wqkb, Wvob);

    // 2) projections: qk = xb @ Wqkb^T (8-phase 256^2) ; vwT = (yb @ Wvob^T)^T
    gemm256_kernel<0, 0><<<dim3(4, 64, 1), 512, 0, stream>>>(xb, Wqkb, qk,
                                                             1024, 512, 512, 0, 0, 0);
    gemm_bt_kernel<1><<<dim3(4, 128, 1), 256, 0, stream>>>(xb + 8388608, Wvob, vwT,
                                                           512, 512, 512, 512, 0, 0, 0);

    // 3) P = exp(q @ k^T) per batch — grouped-swizzle 256x256 kernel
    gemm256_kernel<1, 1><<<dim3(16, 16, 4), 512, 0, stream>>>(qk, qk + 512, P,
                                                              4096, 1024, 1024,
                                                              4194304, 4194304, 16777216);

    // 4) PV split-K partials + inline rowsum — merged-phase kernel
    pv8_kernel<<<256, 512, 0, stream>>>(P, vwT, part, lpart);

    // 5) out = (part0 + part1)/(l0 + l1) + bo
    reduce_kernel<<<8192, 256, 0, stream>>>(part, lpart, bo, out);
}

// Round 18
// 303.971 us; speedup vs baseline: 1.2382x; 1.0199x over previous
//
#include <hip/hip_runtime.h>
#include <hip/hip_bf16.h>

// ---------------------------------------------------------------------------
// Multihead attention (single 512-wide head), b=4, n=4096, d=inner=512, fp32 io.
//   qk = x@[Wq*s | Wk]^T   (merged projection, 8-phase 256^2 kernel)
//   vw = y@(Wo@Wv)^T       (out-proj folded into V), stored transposed as vwT
//   P  = exp(q@k^T)        (no max subtraction: |S| small, fp32-safe)
//   out = (P@vw)/rowsum(P) + bo   (split-K=2 PV + deterministic reduce)
// R18: S-GEMM moved to gemm_db_kernel — 128x256 tile, BK=32 double-buffer,
//      48 KB LDS, 64x64 wave tile (acc 64 regs) -> 2 blocks/CU so independent
//      blocks overlap each other's barrier drains (m114 mechanism).
// ---------------------------------------------------------------------------

typedef unsigned short u16;
typedef __bf16 bf16x8 __attribute__((ext_vector_type(8)));
typedef float f32x4 __attribute__((ext_vector_type(4)));

#define SCALE_QK 0.044194173824159216f /* 1/sqrt(512) */

__device__ __forceinline__ u16 f2bf(float f) {
    __hip_bfloat16 h = __float2bfloat16(f);
    return __builtin_bit_cast(u16, h);
}

__device__ __forceinline__ void load_lds16(const void* g, void* l) {
    __builtin_amdgcn_global_load_lds(
        (const __attribute__((address_space(1))) void*)g,
        (__attribute__((address_space(3))) void*)l, 16, 0, 0);
}

// ---------------- prep: x/y -> bf16, [Wq*s|Wk] -> bf16, Wvo=Wo@Wv -> bf16 ---
__global__ void prep_kernel(const float* __restrict__ x, const float* __restrict__ y,
                            const float* __restrict__ Wq, const float* __restrict__ Wk,
                            const float* __restrict__ Wo, const float* __restrict__ Wv,
                            u16* __restrict__ xb, u16* __restrict__ Wqkb,
                            u16* __restrict__ Wvob) {
    const int b = blockIdx.x, tid = threadIdx.x;
    if (b < 8448) {
        const float *s0, *s1;
        u16* dst;
        int n8, i;
        float sc0, sc1;
        if (b < 8192) { s0 = x;  s1 = y;  dst = xb;   n8 = 1048576; sc0 = 1.f;      sc1 = 1.f; i = b * 256 + tid; }
        else          { s0 = Wq; s1 = Wk; dst = Wqkb; n8 = 32768;   sc0 = SCALE_QK; sc1 = 1.f; i = (b - 8192) * 256 + tid; }
        const float4* s4;
        float scale;
        int j;
        if (i < n8) { s4 = (const float4*)s0; scale = sc0; j = i; }
        else        { s4 = (const float4*)s1; scale = sc1; j = i - n8; }
        float4 v0 = s4[2 * j], v1 = s4[2 * j + 1];
        union { u16 u[8]; uint4 v; } o;
        o.u[0] = f2bf(v0.x * scale); o.u[1] = f2bf(v0.y * scale);
        o.u[2] = f2bf(v0.z * scale); o.u[3] = f2bf(v0.w * scale);
        o.u[4] = f2bf(v1.x * scale); o.u[5] = f2bf(v1.y * scale);
        o.u[6] = f2bf(v1.z * scale); o.u[7] = f2bf(v1.w * scale);
        ((uint4*)dst)[i] = o.v;
    } else {
        // Wvo = Wo @ Wv -> bf16, 4 rows per block (blocks 8448..8575)
        int ob = (b - 8448) * 4, t = tid;
        float a[4][2] = {{0.f, 0.f}, {0.f, 0.f}, {0.f, 0.f}, {0.f, 0.f}};
        for (int i = 0; i < 512; ++i) {
            float v0 = Wv[i * 512 + t], v1 = Wv[i * 512 + t + 256];
#pragma unroll
            for (int r = 0; r < 4; ++r) {
                float w = Wo[(ob + r) * 512 + i];
                a[r][0] += w * v0;
                a[r][1] += w * v1;
            }
        }
#pragma unroll
        for (int r = 0; r < 4; ++r) {
            Wvob[(ob + r) * 512 + t] = f2bf(a[r][0]);
            Wvob[(ob + r) * 512 + t + 256] = f2bf(a[r][1]);
        }
    }
}

// ===========================================================================
// NEW: 128x256-tile double-buffer GEMM, BK=32, 8 waves (2M x 4N of 64x64),
// 48 KB LDS -> 2 blocks/CU (__launch_bounds__(512,4), acc 64 regs/wave).
// One barrier + vmcnt(0) per K-tile. Grid MUST be (16,32,4): L2-grouped
// decode (concurrent 64 blocks/XCD = 8bx x 8by = 3 MB <= L2).
// C = (DOEXP ? exp : id)(A@B^T) -> bf16.
// ===========================================================================
template <int DOEXP>
__launch_bounds__(512, 4)
__global__ void gemm_db_kernel(const u16* __restrict__ A, const u16* __restrict__ B,
                               u16* __restrict__ Cout, int N, int K, int lda, int ldb,
                               long long sAz, long long sBz, long long sCz) {
    __shared__ u16 Asl[2][128 * 32];   // 8 KB per buffer
    __shared__ u16 Bsl[2][256 * 32];   // 16 KB per buffer

    const int tid = threadIdx.x;
    const int wave = tid >> 6, lane = tid & 63;
    const int lr = lane & 15, lg = lane >> 4;
    const int wm = wave >> 2, wn = wave & 3;
    const int rsw = (lg ^ ((lr >> 1) & 3)) << 3;

    // nwg = 2048; lgc -> (loc 8x8, G): z = G&3, bxh = (G>>2)&1, byq = G>>3
    int bid = (blockIdx.z * gridDim.y + blockIdx.y) * gridDim.x + blockIdx.x;
    int lgc = (bid & 7) * 256 + (bid >> 3);
    const int loc = lgc & 63;
    const int G = lgc >> 6;            // 0..31
    const int z = G & 3;
    const int bx = ((G >> 2) & 1) * 8 + (loc & 7);
    const int by = (G >> 3) * 8 + (loc >> 3);
    const int row0 = by * 128, col0 = bx * 256;

    const u16* Ab = A + (size_t)z * sAz;
    const u16* Bb = B + (size_t)z * sBz;

    const int rb = lane >> 2;
    const int kg8 = ((lane & 3) ^ ((rb >> 1) & 3)) << 3;

    f32x4 acc[4][4];
#pragma unroll
    for (int i = 0; i < 4; ++i)
#pragma unroll
        for (int j = 0; j < 4; ++j) acc[i][j] = (f32x4){0.f, 0.f, 0.f, 0.f};

    // stage tile kt: A 128x32 (1 load/thread), B 256x32 (2 loads/thread)
#define STAGE_T(buf_, kt_)                                                        \
    {                                                                             \
        const int kofs_ = (kt_) * 32 + kg8;                                       \
        load_lds16(Ab + (size_t)(row0 + wave * 16 + rb) * lda + kofs_,            \
                   &Asl[buf_][wave * 512]);                                       \
        _Pragma("unroll") for (int j_ = 0; j_ < 2; ++j_) {                        \
            int r_ = (j_ * 8 + wave) * 16 + rb;                                   \
            load_lds16(Bb + (size_t)(col0 + r_) * ldb + kofs_,                    \
                       &Bsl[buf_][(j_ * 8 + wave) * 512]);                        \
        }                                                                         \
    }

    const int KT = K >> 5;
    STAGE_T(0, 0);
#pragma unroll 2
    for (int kt = 0; kt < KT; ++kt) {
        asm volatile("s_waitcnt vmcnt(0)");
        __builtin_amdgcn_s_barrier();
        if (kt + 1 < KT) STAGE_T((kt + 1) & 1, kt + 1);
        const int sl = kt & 1;

        bf16x8 af[4], bfr[4];
#pragma unroll
        for (int f = 0; f < 4; ++f)
            af[f] = *(const bf16x8*)&Asl[sl][(wm * 64 + f * 16 + lr) * 32 + rsw];
#pragma unroll
        for (int f = 0; f < 4; ++f)
            bfr[f] = *(const bf16x8*)&Bsl[sl][(wn * 64 + f * 16 + lr) * 32 + rsw];

        __builtin_amdgcn_s_setprio(1);
#pragma unroll
        for (int f = 0; f < 4; ++f)
#pragma unroll
            for (int n = 0; n < 4; ++n)
                acc[f][n] = __builtin_amdgcn_mfma_f32_16x16x32_bf16(
                    af[f], bfr[n], acc[f][n], 0, 0, 0);
        __builtin_amdgcn_s_setprio(0);
    }
#undef STAGE_T

    // epilogue: row = row0 + wm*64 + fm*16 + lg*4 + reg; col = col0 + wn*64 + fn*16 + lr
    u16* C = Cout + (size_t)z * sCz;
#pragma unroll
    for (int fm = 0; fm < 4; ++fm)
#pragma unroll
        for (int fn = 0; fn < 4; ++fn)
#pragma unroll
            for (int reg = 0; reg < 4; ++reg) {
                int r = row0 + wm * 64 + fm * 16 + lg * 4 + reg;
                int c = col0 + wn * 64 + fn * 16 + lr;
                float v = acc[fm][fn][reg];
                if (DOEXP) v = __expf(v);
                C[(size_t)r * N + c] = f2bf(v);
            }
}

// ===========================================================================
// 256x256 merged-phase GEMM, K=512 (R14 codegen) — used for qk projection.
// ===========================================================================
template <int DOEXP, int GROUPED>
__launch_bounds__(512, 2)
__global__ void gemm256_kernel(const u16* __restrict__ A, const u16* __restrict__ B,
                               u16* __restrict__ Cout, int N, int lda, int ldb,
                               long long sAz, long long sBz, long long sCz) {
    __shared__ u16 lds[8][8192];

    const int tid = threadIdx.x;
    const int wave = tid >> 6, lane = tid & 63;
    const int lr = lane & 15, lg = lane >> 4;
    const int wm = wave >> 2, wn = wave & 3;
    const int rsw = (lg ^ ((lr >> 1) & 3)) << 3;

    const int gx = gridDim.x, gy = gridDim.y;
    int bid = (blockIdx.z * gy + blockIdx.y) * gx + blockIdx.x;
    const int nwg = gx * gy * gridDim.z;
    int lgc = (bid & 7) * (nwg >> 3) + (bid >> 3);
    int bx, by, z;
    if (GROUPED) {
        z = lgc >> 8;
        int r = lgc & 255;
        int g = r >> 5, loc = r & 31;
        bx = (g & 3) * 4 + (loc & 3);
        by = (g >> 2) * 8 + (loc >> 2);
    } else {
        bx = lgc % gx;
        int rem = lgc / gx;
        by = rem % gy;
        z = rem / gy;
    }
    const int row0 = by * 256, col0 = bx * 256;

    const u16* Ab = A + (size_t)z * sAz;
    const u16* Bb = B + (size_t)z * sBz;

    const int rb = lane >> 2;
    const int kg8 = ((lane & 3) ^ ((rb >> 1) & 3)) << 3;

    f32x4 acc[8][4];
#pragma unroll
    for (int i = 0; i < 8; ++i)
#pragma unroll
        for (int j = 0; j < 4; ++j) acc[i][j] = (f32x4){0.f, 0.f, 0.f, 0.f};

#define STAGE_HALF(s_, slot_)                                                     \
    {                                                                             \
        const int h_ = (s_)&3, ts_ = (s_) >> 2;                                   \
        const u16* G_ = (h_ & 1) ? Bb : Ab;                                       \
        const int pan_ = (h_ & 1) ? col0 : row0;                                  \
        const int ld_ = (h_ & 1) ? ldb : lda;                                     \
        const int kofs_ = ts_ * 64 + (h_ >> 1) * 32 + kg8;                        \
        _Pragma("unroll") for (int j_ = 0; j_ < 2; ++j_) {                        \
            int r_ = (j_ * 8 + wave) * 16 + rb;                                   \
            load_lds16(G_ + (size_t)(pan_ + r_) * ld_ + kofs_,                    \
                       &lds[slot_][(j_ * 8 + wave) * 512]);                       \
        }                                                                         \
    }

    #pragma unroll
    for (int s = 0; s < 6; ++s) STAGE_HALF(s, s);
    asm volatile("s_waitcnt vmcnt(4)");
    __builtin_amdgcn_s_barrier();

#pragma unroll
    for (int i = 0; i < 4; ++i) {
#pragma unroll
        for (int m = 0; m < 4; ++m) {
            const int sub = m & 1;
            const int tp = (m >> 1) & 1;
            const int aslot = tp * 4 + 2 * sub;
            const int bslot = aslot + 1;

            bf16x8 af[8];
#pragma unroll
            for (int f = 0; f < 8; ++f) {
                int row = wm * 128 + f * 16 + lr;
                af[f] = *(const bf16x8*)&lds[aslot][row * 32 + rsw];
            }
            bf16x8 bfr[4];
#pragma unroll
            for (int f = 0; f < 4; ++f) {
                int row = wn * 64 + f * 16 + lr;
                bfr[f] = *(const bf16x8*)&lds[bslot][row * 32 + rsw];
            }

            {
                const int s0 = 8 * i + 2 * m + 6;
                if (s0 < 32) STAGE_HALF(s0, (2 * m + 6) & 7);
                if (s0 + 1 < 32) STAGE_HALF(s0 + 1, (2 * m + 7) & 7);
            }

            __builtin_amdgcn_s_barrier();

            __builtin_amdgcn_s_setprio(1);
#pragma unroll
            for (int f = 0; f < 8; ++f)
#pragma unroll
                for (int n = 0; n < 4; ++n)
                    acc[f][n] = __builtin_amdgcn_mfma_f32_16x16x32_bf16(
                        af[f], bfr[n], acc[f][n], 0, 0, 0);
            __builtin_amdgcn_s_setprio(0);

            if (sub == 1) {
                if (i == 3 && m == 1) asm volatile("s_waitcnt vmcnt(0)");
                else                  asm volatile("s_waitcnt vmcnt(4)");
            }
            __builtin_amdgcn_s_barrier();
        }
    }
#undef STAGE_HALF

    u16* C = Cout + (size_t)z * sCz;
#pragma unroll
    for (int fm = 0; fm < 8; ++fm)
#pragma unroll
        for (int fn = 0; fn < 4; ++fn)
#pragma unroll
            for (int reg = 0; reg < 4; ++reg) {
                int r = row0 + wm * 128 + fm * 16 + lg * 4 + reg;
                int c = col0 + wn * 64 + fn * 16 + lr;
                float v = acc[fm][fn][reg];
                if (DOEXP) v = __expf(v);
                C[(size_t)r * N + c] = f2bf(v);
            }
}

// ===========================================================================
// 256x256 PV: part[ks] = P[:, ks-half] @ vw[ks-half], inline rowsum.
// 256 blocks (1/CU), 32 K-tiles = 64 merged phases. lda = ldb = 4096.
// ===========================================================================
__launch_bounds__(512, 2)
__global__ void pv8_kernel(const u16* __restrict__ P, const u16* __restrict__ vwT,
                           float* __restrict__ part, float* __restrict__ lpart) {
    __shared__ u16 lds[8][8192];

    const int tid = threadIdx.x;
    const int wave = tid >> 6, lane = tid & 63;
    const int lr = lane & 15, lg = lane >> 4;
    const int wm = wave >> 2, wn = wave & 3;
    const int rsw = (lg ^ ((lr >> 1) & 3)) << 3;

    int bid = blockIdx.x;
    int lgc = (bid & 7) * 32 + (bid >> 3);
    const int rp = lgc & 15;
    const int t5 = lgc >> 4;
    const int cx = t5 & 1, ks = (t5 >> 1) & 1, z = t5 >> 2;
    const int row0 = rp * 256;
    const int col0 = cx * 256;

    const u16* Ab = P + (size_t)z * 16777216 + (size_t)ks * 2048;
    const u16* Bb = vwT + (size_t)z * 2097152 + (size_t)ks * 2048;

    const int rb = lane >> 2;
    const int kg8 = ((lane & 3) ^ ((rb >> 1) & 3)) << 3;

    f32x4 acc[8][4];
#pragma unroll
    for (int i = 0; i < 8; ++i)
#pragma unroll
        for (int j = 0; j < 4; ++j) acc[i][j] = (f32x4){0.f, 0.f, 0.f, 0.f};
    float rsm[8] = {0.f, 0.f, 0.f, 0.f, 0.f, 0.f, 0.f, 0.f};

#define STAGE_HALF(s_, slot_)                                                     \
    {                                                                             \
        const int h_ = (s_)&3, ts_ = (s_) >> 2;                                   \
        const u16* G_ = (h_ & 1) ? Bb : Ab;                                       \
        const int pan_ = (h_ & 1) ? col0 : row0;                                  \
        const int kofs_ = ts_ * 64 + (h_ >> 1) * 32 + kg8;                        \
        _Pragma("unroll") for (int j_ = 0; j_ < 2; ++j_) {                        \
            int r_ = (j_ * 8 + wave) * 16 + rb;                                   \
            load_lds16(G_ + (size_t)(pan_ + r_) * 4096 + kofs_,                   \
                       &lds[slot_][(j_ * 8 + wave) * 512]);                       \
        }                                                                         \
    }

    #pragma unroll
    for (int s = 0; s < 6; ++s) STAGE_HALF(s, s);
    asm volatile("s_waitcnt vmcnt(4)");
    __builtin_amdgcn_s_barrier();

    for (int i = 0; i < 16; ++i) {
#pragma unroll
        for (int m = 0; m < 4; ++m) {
            const int sub = m & 1;
            const int tp = (m >> 1) & 1;
            const int aslot = tp * 4 + 2 * sub;
            const int bslot = aslot + 1;

            bf16x8 af[8];
#pragma unroll
            for (int f = 0; f < 8; ++f) {
                int row = wm * 128 + f * 16 + lr;
                af[f] = *(const bf16x8*)&lds[aslot][row * 32 + rsw];
            }
            bf16x8 bfr[4];
#pragma unroll
            for (int f = 0; f < 4; ++f) {
                int row = wn * 64 + f * 16 + lr;
                bfr[f] = *(const bf16x8*)&lds[bslot][row * 32 + rsw];
            }

            {
                const int s0 = 8 * i + 2 * m + 6;
                if (s0 < 128) STAGE_HALF(s0, (2 * m + 6) & 7);
                if (s0 + 1 < 128) STAGE_HALF(s0 + 1, (2 * m + 7) & 7);
            }

            __builtin_amdgcn_s_barrier();

            __builtin_amdgcn_s_setprio(1);
#pragma unroll
            for (int f = 0; f < 8; ++f)
#pragma unroll
                for (int n = 0; n < 4; ++n)
                    acc[f][n] = __builtin_amdgcn_mfma_f32_16x16x32_bf16(
                        af[f], bfr[n], acc[f][n], 0, 0, 0);
            __builtin_amdgcn_s_setprio(0);

            if (wn == 0) {
#pragma unroll
                for (int f = 0; f < 8; ++f) {
                    union { bf16x8 v; unsigned u[4]; } cv;
                    cv.v = af[f];
#pragma unroll
                    for (int w = 0; w < 4; ++w)
                        rsm[f] += __uint_as_float(cv.u[w] << 16) +
                                  __uint_as_float(cv.u[w] & 0xffff0000u);
                }
            }

            if (sub == 1) {
                if (i == 15 && m == 1) asm volatile("s_waitcnt vmcnt(0)");
                else                   asm volatile("s_waitcnt vmcnt(4)");
            }
            __builtin_amdgcn_s_barrier();
        }
    }
#undef STAGE_HALF

    if (wn == 0) {
#pragma unroll
        for (int j = 0; j < 8; ++j) {
            rsm[j] += __shfl_xor(rsm[j], 16, 64);
            rsm[j] += __shfl_xor(rsm[j], 32, 64);
        }
        if (cx == 0 && lg == 0) {
            float* lp = lpart + (size_t)ks * 16384 + z * 4096 + row0 + wm * 128;
#pragma unroll
            for (int j = 0; j < 8; ++j) lp[j * 16 + lr] = rsm[j];
        }
    }

    float* O = part + (size_t)ks * 8388608 + ((size_t)z * 4096 + row0) * 512;
#pragma unroll
    for (int fm = 0; fm < 8; ++fm)
#pragma unroll
        for (int fn = 0; fn < 4; ++fn) {
            int c = col0 + wn * 64 + fn * 16 + lr;
#pragma unroll
            for (int reg = 0; reg < 4; ++reg) {
                int r = wm * 128 + fm * 16 + lg * 4 + reg;
                O[(size_t)r * 512 + c] = acc[fm][fn][reg];
            }
        }
}

// --------------------------- GEMM: C = A @ B^T (m97 128x128) ----------------
// EPI 1: bf16 TRANSPOSED store to vwT[batch][col][row&4095]  (vwT projection)
template <int EPI>
__launch_bounds__(256)
__global__ void gemm_bt_kernel(const u16* __restrict__ A, const u16* __restrict__ B,
                               void* __restrict__ Cout, int N, int K, int lda, int ldb,
                               long long sAz, long long sBz, long long sCz) {
    __shared__ u16 As[2][128 * 32];
    __shared__ u16 Bs[2][128 * 32];

    const int tid = threadIdx.x;
    const int wave = tid >> 6, lane = tid & 63;
    const int lr = lane & 15, lg = lane >> 4;
    const int wr = wave >> 1, wc = wave & 1;

    const int gx = gridDim.x, gy = gridDim.y;
    int bid = (blockIdx.z * gy + blockIdx.y) * gx + blockIdx.x;
    const int nwg = gx * gy * gridDim.z;
    int lgc = (bid & 7) * (nwg >> 3) + (bid >> 3);
    const int bx = lgc % gx;
    int rem = lgc / gx;
    const int by = rem % gy, z = rem / gy;
    const int row0 = by * 128, col0 = bx * 128;

    const u16* Ab = A + (size_t)z * sAz;
    const u16* Bb = B + (size_t)z * sBz;

    f32x4 acc[4][4];
#pragma unroll
    for (int i = 0; i < 4; ++i)
#pragma unroll
        for (int j = 0; j < 4; ++j) acc[i][j] = (f32x4){0.f, 0.f, 0.f, 0.f};

    const int KT = K >> 5;

#define STAGE(bufi, kt2)                                                          \
    {                                                                             \
        _Pragma("unroll") for (int i = 0; i < 2; ++i) {                           \
            int chunk = i * 256 + tid;                                            \
            int r = chunk >> 2, c4 = chunk & 3;                                   \
            load_lds16(Ab + (size_t)(row0 + r) * lda + (kt2) * 32 + c4 * 8,       \
                       &As[bufi][(i * 256 + wave * 64) * 8]);                     \
            load_lds16(Bb + (size_t)(col0 + r) * ldb + (kt2) * 32 + c4 * 8,       \
                       &Bs[bufi][(i * 256 + wave * 64) * 8]);                     \
        }                                                                         \
    }

    STAGE(0, 0);
    int buf = 0;
    for (int kt = 0; kt < KT; ++kt) {
        __syncthreads();
        if (kt + 1 < KT) STAGE(buf ^ 1, kt + 1);

        bf16x8 af[4], bfr[4];
#pragma unroll
        for (int mf = 0; mf < 4; ++mf)
            af[mf] = *(const bf16x8*)&As[buf][(wr * 64 + mf * 16 + lr) * 32 + lg * 8];
#pragma unroll
        for (int nf = 0; nf < 4; ++nf)
            bfr[nf] = *(const bf16x8*)&Bs[buf][(wc * 64 + nf * 16 + lr) * 32 + lg * 8];
#pragma unroll
        for (int mf = 0; mf < 4; ++mf)
#pragma unroll
            for (int nf = 0; nf < 4; ++nf)
                acc[mf][nf] = __builtin_amdgcn_mfma_f32_16x16x32_bf16(
                    af[mf], bfr[nf], acc[mf][nf], 0, 0, 0);
        buf ^= 1;
    }
#undef STAGE

    const int rbase = row0 + wr * 64;
    const int cbase = col0 + wc * 64;

    if (EPI == 0) {
        u16* C = (u16*)Cout + (size_t)z * sCz;
#pragma unroll
        for (int mf = 0; mf < 4; ++mf)
#pragma unroll
            for (int nf = 0; nf < 4; ++nf)
#pragma unroll
                for (int reg = 0; reg < 4; ++reg) {
                    int r = rbase + mf * 16 + lg * 4 + reg;
                    int c = cbase + nf * 16 + lr;
                    C[(size_t)r * N + c] = f2bf(acc[mf][nf][reg]);
                }
    } else {  // EPI == 1: transposed store vwT[batch][col][row%4096]
        u16* C = (u16*)Cout;
#pragma unroll
        for (int mf = 0; mf < 4; ++mf)
#pragma unroll
            for (int nf = 0; nf < 4; ++nf) {
                int rg = rbase + mf * 16 + lg * 4;
                int bsel = rg >> 12, rl = rg & 4095;
                int c = cbase + nf * 16 + lr;
                union { u16 u[4]; uint2 v; } o;
#pragma unroll
                for (int reg = 0; reg < 4; ++reg) o.u[reg] = f2bf(acc[mf][nf][reg]);
                *(uint2*)(C + ((size_t)bsel << 21) + ((size_t)c << 12) + rl) = o.v;
            }
    }
}

// --------------------------- reduce: out = (p0+p1)/l + bo -------------------
__global__ void reduce_kernel(const float* __restrict__ part,
                              const float* __restrict__ lpart,
                              const float* __restrict__ bo,
                              float* __restrict__ out) {
    int i = blockIdx.x * blockDim.x + threadIdx.x;
    int r = i >> 7, c4 = i & 127;
    float inv = 1.0f / (lpart[r] + lpart[16384 + r]);
    float4 a = ((const float4*)part)[i];
    float4 b = ((const float4*)part)[i + 2097152];
    float4 bi = ((const float4*)bo)[c4];
    float4 o;
    o.x = (a.x + b.x) * inv + bi.x;
    o.y = (a.y + b.y) * inv + bi.y;
    o.z = (a.z + b.z) * inv + bi.z;
    o.w = (a.w + b.w) * inv + bi.w;
    ((float4*)out)[i] = o;
}

// ---------------------------------------------------------------------------
extern "C" void kernel_launch(void* const* d_in, const int* in_sizes, int n_in,
                              void* d_out, int out_size, void* d_ws, size_t ws_size,
                              hipStream_t stream) {
    const float* x  = (const float*)d_in[0];
    const float* y  = (const float*)d_in[1];
    const float* Wq = (const float*)d_in[2];
    const float* Wk = (const float*)d_in[3];
    const float* Wv = (const float*)d_in[4];
    const float* Wo = (const float*)d_in[5];
    const float* bo = (const float*)d_in[6];
    float* out = (float*)d_out;

    char* ws = (char*)d_ws;
    u16*   xb   = (u16*)(ws + 0);            // 16 MB (16384 x 512); yb follows
    u16*   qk   = (u16*)(ws + 33554432);     // 32 MB (16384 x 1024: q|k)
    float* part = (float*)(ws + 0);          // 64 MB [2][16384][512] (reuses xb/yb/qk)
    u16*   vwT  = (u16*)(ws + 67108864);     // 16 MB [4][512][4096]
    u16*   Wqkb = (u16*)(ws + 83886080);     // 1 MB  (1024 x 512)
    u16*   Wvob = (u16*)(ws + 84934656);     // 512 KB
    float* lpart= (float*)(ws + 86507520);   // 128 KB [2][16384]
    u16*   P    = (u16*)(ws + 86638592);     // 128 MB [4][4096][4096]

    // 1) single prep launch: x/y -> bf16, [Wq*s|Wk] -> bf16, Wvo=Wo@Wv -> bf16
    prep_kernel<<<8576, 256, 0, stream>>>(x, y, Wq, Wk, Wo, Wv, xb, Wqkb, Wvob);

    // 2) projections: qk = xb @ Wqkb^T (8-phase 256^2) ; vwT = (yb @ Wvob^T)^T
    gemm256_kernel<0, 0><<<dim3(4, 64, 1), 512, 0, stream>>>(xb, Wqkb, qk,
                                                             1024, 512, 512, 0, 0, 0);
    gemm_bt_kernel<1><<<dim3(4, 128, 1), 256, 0, stream>>>(xb + 8388608, Wvob, vwT,
                                                           512, 512, 512, 512, 0, 0, 0);

    // 3) P = exp(q @ k^T) — NEW 128x256 double-buffer kernel, 2 blocks/CU
    gemm_db_kernel<1><<<dim3(16, 32, 4), 512, 0, stream>>>(qk, qk + 512, P,
                                                           4096, 512, 1024, 1024,
                                                           4194304, 4194304, 16777216);

    // 4) PV split-K partials + inline rowsum — merged-phase kernel
    pv8_kernel<<<256, 512, 0, stream>>>(P, vwT, part, lpart);

    // 5) out = (part0 + part1)/(l0 + l1) + bo
    reduce_kernel<<<8192, 256, 0, stream>>>(part, lpart, bo, out);
}